// Round 2
// baseline (1171.944 us; speedup 1.0000x reference)
//
#include <hip/hip_runtime.h>
#include <cmath>
#include <cstdint>
#include <cstddef>

#define BB 8
#define EE 1024
#define SS 2000
#define HH 16
#define HDIM 64
#define MLM 10
#define MLPD 4096
#define QKV_N 3072
#define MPAD 16384  // 64*256 padded row count: every gemm grid divisible by 8 XCDs
#define QK_SCALE 0.35355339059327373f

typedef __attribute__((ext_vector_type(8))) short short8v;
typedef __attribute__((ext_vector_type(4))) float f32x4;

static __device__ __forceinline__ short f2bf(float x) {
  unsigned u = __builtin_bit_cast(unsigned, x);
  unsigned r = (u + 0x7fffu + ((u >> 16) & 1u)) >> 16;
  return (short)(unsigned short)r;
}
static __device__ __forceinline__ float bf2f(short x) {
  unsigned u = ((unsigned)(unsigned short)x) << 16;
  return __builtin_bit_cast(float, u);
}

// async global->LDS, 16B per lane; LDS dest is wave-uniform base + lane*16
static __device__ __forceinline__ void load_lds16(const short* g, short* l) {
  __builtin_amdgcn_global_load_lds(
      (const __attribute__((address_space(1))) void*)g,
      (__attribute__((address_space(3))) void*)l, 16, 0, 0);
}

// ---------------- X (B,E,S) f32 -> xb (B,S,E) bf16 ----------------
__global__ __launch_bounds__(256) void transpose_x(const float* __restrict__ X, short* __restrict__ xb) {
  __shared__ float tile[32][33];
  int b = blockIdx.z;
  int e0 = blockIdx.y * 32;
  int s0 = blockIdx.x * 32;
  int tx = threadIdx.x;      // 0..31
  int ty = threadIdx.y;      // 0..7
#pragma unroll
  for (int i = 0; i < 32; i += 8) {
    int e = e0 + ty + i, s = s0 + tx;
    tile[ty + i][tx] = (s < SS) ? X[((size_t)b * EE + e) * SS + s] : 0.f;
  }
  __syncthreads();
#pragma unroll
  for (int i = 0; i < 32; i += 8) {
    int s = s0 + ty + i, e = e0 + tx;
    if (s < SS) xb[((size_t)b * SS + s) * EE + e] = f2bf(tile[tx][ty + i]);
  }
}

// ---------------- f32 -> bf16 cast ----------------
__global__ __launch_bounds__(256) void cast_f2b(const float* __restrict__ src, short* __restrict__ dst, int n) {
  int i = blockIdx.x * 256 + threadIdx.x;
  int stride = gridDim.x * 256;
  for (; i < n; i += stride) dst[i] = f2bf(src[i]);
}

// =====================================================================
// 256x256xBK=64 8-phase bf16 GEMM, fragment-major LDS (zero-conflict).
// C[m,n] = sum_k A[m,k]*Bm[n,k]  (both operands row-major [out][K])
// 8 waves (512 thr): wave (wm,wn) owns a 128x64 output sub-tile.
// LDS 128 KiB: 2 dbuf x {A,B} x {k-half} x 16 KiB region.
// Region layout = FRAGMENT-MAJOR: 16 blocks of 1 KiB; block mi holds the
// 16x32 bf16 subtile in MFMA lane order (lane l = rows mi*16+(l&15),
// k = (l>>4)*8..+7). ds_read_b128 at base+lane*16 => 64 lanes contiguous
// 1 KiB => each 8-lane phase covers all 32 banks once: ZERO conflicts.
// Write side: global_load_lds writes base+lane*16 linearly; the GLOBAL
// source address is permuted per staging lane so the linear write lands
// fragment-major (swizzle-on-source, identity-on-read).
// T3/T4: 1 half-tile (2x gload_lds) staged per phase; vmcnt(6) at phases
// 4 and 8 only (3 half-tiles in flight); last iteration peeled (drain).
// T5: setprio(1) around each 16-MFMA cluster.
// XCD map: xcd=bid&7 owns an 8-m-tile slice (A-slice ~4MB L2-resident),
// sweeps m fastest then n (B-tile fetched once per column per XCD).
// =====================================================================
__global__ __launch_bounds__(512, 2) void gemm256(
    const short* __restrict__ A, const short* __restrict__ Bm, void* __restrict__ Cv,
    int K, int N, int mode, int Mstore,
    const float* __restrict__ p0, const float* __restrict__ p1, const float* __restrict__ p2)
{
  __shared__ __align__(16) short lds[65536];  // 128 KiB
  const int tid = threadIdx.x;

  // ---- XCD-aware tile mapping: grid = NT_N * 64, NT_M = 64 ----
  const int xcd = blockIdx.x & 7;
  const int idx = blockIdx.x >> 3;
  const int m0 = (((xcd << 3) | (idx & 7))) << 8;  // 64 m-tiles, 8 per XCD
  const int n0 = (idx >> 3) << 8;

  const int lane = tid & 63, wv = tid >> 6;
  const int wm = wv >> 2, wn = wv & 3;          // 2 x 4 wave grid
  const int lm = lane & 15, quad = lane >> 4;
  // fragment-major read offsets (shorts): block = 512 shorts = 1 KiB
  const int aoff = wm * 4096 + lane * 8;        // wm*8 blocks
  const int boff = wn * 2048 + lane * 8;        // wn*4 blocks

  // staging: thread t fetches the 16B that belongs at LDS slot t (linear dest).
  // slot t = block (t>>6), lane (t&63): row = (t>>6)*16 + (t&15), kslot = (t>>4)&3
  const int srow = ((tid >> 6) << 4) + (tid & 15);
  const int sk = ((tid >> 4) & 3) << 3;         // shorts: 0,8,16,24
  const short* Ag = A + (size_t)(m0 + srow) * K + sk;
  const short* Bg = Bm + (size_t)(n0 + srow) * K + sk;
  const int wofs = (tid >> 6) << 9;             // wave-uniform LDS chunk (shorts)

  f32x4 acc[8][4];
#pragma unroll
  for (int i = 0; i < 8; i++)
#pragma unroll
    for (int j = 0; j < 4; j++) acc[i][j] = (f32x4){0.f, 0.f, 0.f, 0.f};
  short8v afr[8], bfr[4];

// region(buf,op,kh) = 8192-short (16 KiB) block
#define RGN(buf, op, kh) (&lds[((((buf)*2 + (op)) * 2 + (kh)) << 13)])
#define STG(op, buf, kh, kt) do {                                          \
    const short* gp_ = ((op) ? Bg : Ag) + ((kt) * 64 + (kh) * 32);         \
    short* lp_ = RGN(buf, op, kh) + wofs;                                  \
    load_lds16(gp_, lp_);                                                  \
    load_lds16(gp_ + (size_t)128 * K, lp_ + 4096);                         \
  } while (0)
#define LDA(buf, kh) do {                                                  \
    const short* r_ = RGN(buf, 0, kh) + aoff;                              \
    _Pragma("unroll") for (int i_ = 0; i_ < 8; ++i_)                       \
      afr[i_] = *(const short8v*)(r_ + i_ * 512);                          \
  } while (0)
#define LDB(buf, kh, jb) do {                                              \
    const short* r_ = RGN(buf, 1, kh) + boff;                              \
    bfr[jb]     = *(const short8v*)(r_ + (jb) * 512);                      \
    bfr[(jb)+1] = *(const short8v*)(r_ + ((jb)+1) * 512);                  \
  } while (0)
#define MM(jb) do {                                                        \
    __builtin_amdgcn_s_setprio(1);                                         \
    _Pragma("unroll") for (int i_ = 0; i_ < 8; ++i_) {                     \
      acc[i_][jb]     = __builtin_amdgcn_mfma_f32_16x16x32_bf16(           \
          afr[i_], bfr[jb],     acc[i_][jb],     0, 0, 0);                 \
      acc[i_][(jb)+1] = __builtin_amdgcn_mfma_f32_16x16x32_bf16(           \
          afr[i_], bfr[(jb)+1], acc[i_][(jb)+1], 0, 0, 0);                 \
    }                                                                      \
    __builtin_amdgcn_s_setprio(0);                                         \
  } while (0)
#define SBAR() do {                                                        \
    __builtin_amdgcn_sched_barrier(0);                                     \
    __builtin_amdgcn_s_barrier();                                          \
    __builtin_amdgcn_sched_barrier(0);                                     \
  } while (0)
#define WAITV(n) asm volatile("s_waitcnt vmcnt(" #n ")" ::: "memory")

// One iteration = 2 K-tiles (2it->buf0 phases 1-4, 2it+1->buf1 phases 5-8).
// Stage ledger (each stage >= 1 barrier after its region's last read):
//  P1: buf1.B.k1 tile 2it+1 | P2: buf0.A.k0 t+2 | P3: buf0.B.k0 | P4: buf0.A.k1
//  P5: buf0.B.k1 | P6: buf1.A.k0 t+3 | P7: buf1.B.k0 | P8: buf1.A.k1
// vmcnt(6)@P4 -> buf1 tile 2it+1 fully resident; @P8 -> buf0 tile 2it+2.
#define ITER(it, LAST) do {                                                              \
    LDB(0,0,0); LDA(0,0); STG(1,1,1, 2*(it)+1);                   SBAR(); MM(0); SBAR(); \
    LDB(0,0,2);           if (!(LAST)) STG(0,0,0, 2*(it)+2);      SBAR(); MM(2); SBAR(); \
    LDB(0,1,0); LDA(0,1); if (!(LAST)) STG(1,0,0, 2*(it)+2);      SBAR(); MM(0); SBAR(); \
    LDB(0,1,2);           if (!(LAST)) { STG(0,0,1, 2*(it)+2); WAITV(6); }               \
                          else         { WAITV(0); }              SBAR(); MM(2); SBAR(); \
    LDB(1,0,0); LDA(1,0); if (!(LAST)) STG(1,0,1, 2*(it)+2);      SBAR(); MM(0); SBAR(); \
    LDB(1,0,2);           if (!(LAST)) STG(0,1,0, 2*(it)+3);      SBAR(); MM(2); SBAR(); \
    LDB(1,1,0); LDA(1,1); if (!(LAST)) STG(1,1,0, 2*(it)+3);      SBAR(); MM(0); SBAR(); \
    LDB(1,1,2);           if (!(LAST)) { STG(0,1,1, 2*(it)+3); WAITV(6); }               \
                                                                  SBAR(); MM(2); SBAR(); \
  } while (0)

  const int NI = K >> 7;  // iterations (2 K-tiles each)
  // prologue: tile0 full -> buf0; tile1 {A.k0,B.k0,A.k1} -> buf1 (B.k1 at P1)
  STG(0,0,0, 0); STG(1,0,0, 0); STG(0,0,1, 0); STG(1,0,1, 0);
  STG(0,1,0, 1); STG(1,1,0, 1); STG(0,1,1, 1);
  WAITV(6);  // retire tile0's 8 loads; tile1's 6 stay in flight
  SBAR();

  for (int it = 0; it < NI - 1; ++it) ITER(it, 0);
  ITER(NI - 1, 1);

  // ---- epilogue ----
  const int crow0 = m0 + wm * 128 + quad * 4;
  const int ccol0 = n0 + wn * 64 + lm;
#pragma unroll
  for (int j = 0; j < 4; ++j) {
    const int col = ccol0 + j * 16;
    float bias, scl = 1.f;
    if (mode == 0) {
      if (col < 1024)      { bias = p0[col];        scl = QK_SCALE; }
      else if (col < 2048) { bias = p1[col - 1024]; scl = QK_SCALE; }
      else                 { bias = p2[col - 2048]; }
    } else {
      bias = p0[col];
    }
#pragma unroll
    for (int i = 0; i < 8; ++i) {
#pragma unroll
      for (int r = 0; r < 4; ++r) {
        const int row = crow0 + i * 16 + r;
        if (row < Mstore) {
          float v = acc[i][j][r] + bias;
          if (mode == 0)      v *= scl;
          else if (mode == 1) v = 0.5f * v * (1.f + erff(v * 0.70710678118f));
          if (mode == 2) ((float*)Cv)[(size_t)row * N + col] = v;
          else           ((short*)Cv)[(size_t)row * N + col] = f2bf(v);
        }
      }
    }
  }
#undef RGN
#undef STG
#undef LDA
#undef LDB
#undef MM
#undef SBAR
#undef WAITV
#undef ITER
}

// ---------------- landmarks: mean over 200-row segments ----------------
__global__ __launch_bounds__(64) void landmarks(const short* __restrict__ QKV, float* __restrict__ Ql, float* __restrict__ Kl) {
  int d = threadIdx.x;
  int bhm = blockIdx.x;
  int part = blockIdx.y;
  int b = bhm / (HH * MLM);
  int h = (bhm / MLM) % HH;
  int m = bhm % MLM;
  const short* src = QKV + (part ? 1024 : 0);
  size_t base = ((size_t)(b * SS + m * 200)) * QKV_N + h * HDIM + d;
  float acc = 0.f;
  for (int i = 0; i < 200; i++) acc += bf2f(src[base + (size_t)i * QKV_N]);
  float* dst = part ? Kl : Ql;
  dst[((size_t)(b * HH + h) * MLM + m) * HDIM + d] = acc * (1.f / 200.f);
}

// ---------------- k2 = softmax(Ql Kl^T) + per-bh col-sum/row-sum maxima ----------------
__global__ __launch_bounds__(128) void k2stats(const float* __restrict__ Ql, const float* __restrict__ Kl,
                                               float* __restrict__ k2, float* __restrict__ cmax, float* __restrict__ rmax) {
  int bh = blockIdx.x;
  __shared__ float QlS[640], KlS[640], zz[100], k2s[100], cs[10], rs[10];
  for (int i = threadIdx.x; i < 640; i += 128) {
    QlS[i] = Ql[(size_t)bh * 640 + i];
    KlS[i] = Kl[(size_t)bh * 640 + i];
  }
  __syncthreads();
  if (threadIdx.x < 100) {
    int i = threadIdx.x / 10, j = threadIdx.x % 10;
    float z = 0.f;
    for (int d = 0; d < 64; d++) z += QlS[i * 64 + d] * KlS[j * 64 + d];
    zz[threadIdx.x] = z;
  }
  __syncthreads();
  if (threadIdx.x < 10) {
    int i = threadIdx.x;
    float mx = -1e30f;
    for (int j = 0; j < 10; j++) mx = fmaxf(mx, zz[i * 10 + j]);
    float s = 0.f, e[10];
    for (int j = 0; j < 10; j++) { e[j] = expf(zz[i * 10 + j] - mx); s += e[j]; }
    float inv = 1.f / s, rsum = 0.f;
    for (int j = 0; j < 10; j++) {
      float v = e[j] * inv;
      k2s[i * 10 + j] = v;
      k2[(size_t)bh * 100 + i * 10 + j] = v;
      rsum += v;
    }
    rs[i] = rsum;
  }
  __syncthreads();
  if (threadIdx.x < 10) {
    int j = threadIdx.x;
    float c = 0.f;
    for (int i = 0; i < 10; i++) c += k2s[i * 10 + j];
    cs[j] = c;
  }
  __syncthreads();
  if (threadIdx.x == 0) {
    float m1 = 0.f, m2 = 0.f;
    for (int j = 0; j < 10; j++) { m1 = fmaxf(m1, cs[j]); m2 = fmaxf(m2, rs[j]); }
    cmax[bh] = m1;
    rmax[bh] = m2;
  }
}

// ---------------- Newton-Schulz pseudo-inverse of k2 (10x10), 6 iters ----------------
__global__ __launch_bounds__(128) void invk(const float* __restrict__ k2, const float* __restrict__ cmax,
                                            const float* __restrict__ rmax, float* __restrict__ invo) {
  int bh = blockIdx.x;
  __shared__ float gsc;
  __shared__ float Km[100], Vm[100], KV[100], Ta[100], Tb[100];
  if (threadIdx.x == 0) {
    float mc = 0.f, mr = 0.f;
    for (int i = 0; i < 128; i++) { mc = fmaxf(mc, cmax[i]); mr = fmaxf(mr, rmax[i]); }
    gsc = 1.f / (mc * mr);
  }
  for (int i = threadIdx.x; i < 100; i += 128) Km[i] = k2[(size_t)bh * 100 + i];
  __syncthreads();
  int t = threadIdx.x;
  int i = t / 10, j = t % 10;
  bool act = t < 100;
  if (act) Vm[t] = Km[j * 10 + i] * gsc;
  __syncthreads();
  for (int it = 0; it < 6; it++) {
    if (act) { float a = 0.f; for (int k = 0; k < 10; k++) a += Km[i * 10 + k] * Vm[k * 10 + j]; KV[t] = a; }
    __syncthreads();
    if (act) Ta[t] = (i == j ? 7.f : 0.f) - KV[t];
    __syncthreads();
    if (act) { float a = 0.f; for (int k = 0; k < 10; k++) a += KV[i * 10 + k] * Ta[k * 10 + j]; Tb[t] = (i == j ? 15.f : 0.f) - a; }
    __syncthreads();
    if (act) { float a = 0.f; for (int k = 0; k < 10; k++) a += KV[i * 10 + k] * Tb[k * 10 + j]; Ta[t] = (i == j ? 13.f : 0.f) - a; }
    __syncthreads();
    if (act) { float a = 0.f; for (int k = 0; k < 10; k++) a += Vm[i * 10 + k] * Ta[k * 10 + j]; Tb[t] = 0.25f * a; }
    __syncthreads();
    if (act) Vm[t] = Tb[t];
    __syncthreads();
  }
  if (act) invo[(size_t)bh * 100 + t] = Vm[t];
}

// ---------------- k1inv[b,s,h,:] = softmax(Q·Kl^T) @ inv ----------------
__global__ __launch_bounds__(256) void k1inv_kernel(const short* __restrict__ QKV, const float* __restrict__ Kl,
                                                    const float* __restrict__ invg, float* __restrict__ k1inv) {
  int b = blockIdx.y;
  int s0 = blockIdx.x * 16;
  __shared__ float KlS[16 * 650];
  __shared__ float invS[16 * 101];
  for (int idx = threadIdx.x; idx < 16 * 640; idx += 256) {
    int h = idx / 640, r = idx % 640;
    KlS[h * 650 + r] = Kl[(size_t)(b * HH + h) * 640 + r];
  }
  for (int idx = threadIdx.x; idx < 1600; idx += 256) {
    int h = idx / 100, r = idx % 100;
    invS[h * 101 + r] = invg[(size_t)(b * HH + h) * 100 + r];
  }
  __syncthreads();
  int sl = threadIdx.x >> 4, h = threadIdx.x & 15;
  int s = s0 + sl;
  size_t qoff = (size_t)(b * SS + s) * QKV_N + h * HDIM;
  float z[10];
#pragma unroll
  for (int m = 0; m < 10; m++) z[m] = 0.f;
  for (int c = 0; c < 8; c++) {
    short8v qv = *(const short8v*)&QKV[qoff + c * 8];
    float qf[8];
#pragma unroll
    for (int jj = 0; jj < 8; jj++) qf[jj] = bf2f(qv[jj]);
#pragma unroll
    for (int m = 0; m < 10; m++) {
      const float* kl = &KlS[h * 650 + m * 64 + c * 8];
      float a = 0.f;
#pragma unroll
      for (int jj = 0; jj < 8; jj++) a += qf[jj] * kl[jj];
      z[m] += a;
    }
  }
  float mx = z[0];
#pragma unroll
  for (int m = 1; m < 10; m++) mx = fmaxf(mx, z[m]);
  float p[10], ssum = 0.f;
#pragma unroll
  for (int m = 0; m < 10; m++) { p[m] = expf(z[m] - mx); ssum += p[m]; }
  float rinv = 1.f / ssum;
  float* dst = &k1inv[((size_t)(b * SS + s) * HH + h) * MLM];
#pragma unroll
  for (int mm = 0; mm < 10; mm++) {
    float a = 0.f;
#pragma unroll
    for (int jjj = 0; jjj < 10; jjj++) a += p[jjj] * invS[h * 101 + jjj * 10 + mm];
    dst[mm] = a * rinv;
  }
}

// ---------------- kv[b,h,m,:] = softmax_s(Ql·K) @ V  (single-pass) ----------------
__global__ __launch_bounds__(256) void k3v_kernel(const short* __restrict__ QKV, const float* __restrict__ Qlg,
                                                  float* __restrict__ kvout) {
  int bh = blockIdx.x;
  int b = bh >> 4, h = bh & 15;
  __shared__ float Kt[64 * 65];
  __shared__ float Vt[64 * 65];
  __shared__ float eS[10 * 64];
  __shared__ float QlS[640];
  __shared__ float denS[10];
  int tid = threadIdx.x;
  int wave = tid >> 6, lane = tid & 63;
  for (int i = tid; i < 640; i += 256) QlS[i] = Qlg[(size_t)bh * 640 + i];
  float myden = 0.f;
  float accn[3] = {0.f, 0.f, 0.f};
  int rowi = tid >> 2;
  int d0 = (tid & 3) * 16;
  for (int s0 = 0; s0 < SS; s0 += 64) {
    __syncthreads();
    if (s0 + rowi < SS) {
      size_t base = (size_t)(b * SS + s0 + rowi) * QKV_N + h * HDIM + d0;
      short8v k0v = *(const short8v*)&QKV[base + 1024];
      short8v k1v = *(const short8v*)&QKV[base + 1024 + 8];
      short8v v0v = *(const short8v*)&QKV[base + 2048];
      short8v v1v = *(const short8v*)&QKV[base + 2048 + 8];
#pragma unroll
      for (int jj = 0; jj < 8; jj++) {
        Kt[rowi * 65 + d0 + jj]     = bf2f(k0v[jj]);
        Kt[rowi * 65 + d0 + 8 + jj] = bf2f(k1v[jj]);
        Vt[rowi * 65 + d0 + jj]     = bf2f(v0v[jj]);
        Vt[rowi * 65 + d0 + 8 + jj] = bf2f(v1v[jj]);
      }
    }
    __syncthreads();
    for (int mb = 0; mb < 12; mb += 4) {
      int m = mb + wave;
      if (m < 10) {
        float z = 0.f;
        const float* kr = &Kt[lane * 65];
        const float* ql = &QlS[m * 64];
        for (int d = 0; d < 64; d++) z += ql[d] * kr[d];
        eS[m * 64 + lane] = (s0 + lane < SS) ? expf(z) : 0.f;
      }
    }
    __syncthreads();
    if (tid < 10) {
      float a = 0.f;
      for (int slj = 0; slj < 64; slj++) a += eS[tid * 64 + slj];
      myden += a;
    }
#pragma unroll
    for (int ii = 0; ii < 3; ii++) {
      int idx = tid + ii * 256;
      if (idx < 640) {
        int m = idx >> 6, d = idx & 63;
        float a = 0.f;
        for (int slj = 0; slj < 64; slj++) a += eS[m * 64 + slj] * Vt[slj * 65 + d];
        accn[ii] += a;
      }
    }
  }
  if (tid < 10) denS[tid] = myden;
  __syncthreads();
#pragma unroll
  for (int ii = 0; ii < 3; ii++) {
    int idx = tid + ii * 256;
    if (idx < 640) {
      int m = idx >> 6;
      kvout[(size_t)bh * 640 + idx] = accn[ii] / denS[m];
    }
  }
}

// ---------------- attn row = k1inv row @ kv, then LayerNorm(g1,be1) -> bf16 ----------------
__global__ __launch_bounds__(256) void attn_ln1(const float* __restrict__ k1inv, const float* __restrict__ kvg,
                                                const float* __restrict__ g1, const float* __restrict__ be1,
                                                short* __restrict__ h1) {
  int blk = blockIdx.x;
  int b = blk / SS;
  __shared__ float pS[160];
  __shared__ float red[8];
  for (int i = threadIdx.x; i < 160; i += 256) pS[i] = k1inv[(size_t)blk * 160 + i];
  __syncthreads();
  float vals[4], s1 = 0.f, s2 = 0.f;
#pragma unroll
  for (int i = 0; i < 4; i++) {
    int e = threadIdx.x + i * 256;
    int h = e >> 6, d = e & 63;
    const float* kvp = &kvg[((size_t)(b * HH + h) * MLM) * HDIM + d];
    const float* pp = &pS[h * 10];
    float a = 0.f;
#pragma unroll
    for (int m = 0; m < 10; m++) a += pp[m] * kvp[m * 64];
    vals[i] = a; s1 += a; s2 += a * a;
  }
#pragma unroll
  for (int off = 32; off; off >>= 1) { s1 += __shfl_down(s1, off); s2 += __shfl_down(s2, off); }
  int wv = threadIdx.x >> 6;
  if ((threadIdx.x & 63) == 0) { red[wv] = s1; red[4 + wv] = s2; }
  __syncthreads();
  float t1 = red[0] + red[1] + red[2] + red[3];
  float t2 = red[4] + red[5] + red[6] + red[7];
  float mean = t1 * (1.f / 1024.f);
  float var = t2 * (1.f / 1024.f) - mean * mean;
  float ninv = rsqrtf(var + 1e-5f);
#pragma unroll
  for (int i = 0; i < 4; i++) {
    int e = threadIdx.x + i * 256;
    h1[(size_t)blk * EE + e] = f2bf((vals[i] - mean) * ninv * g1[e] + be1[e]);
  }
}

// ---------------- LayerNorm(g2,be2) on f32 rows -> bf16 ----------------
__global__ __launch_bounds__(256) void ln2_kernel(const float* __restrict__ h2, const float* __restrict__ g2,
                                                  const float* __restrict__ be2, short* __restrict__ h3) {
  int blk = blockIdx.x;
  __shared__ float red[8];
  float vals[4], s1 = 0.f, s2 = 0.f;
#pragma unroll
  for (int i = 0; i < 4; i++) {
    int e = threadIdx.x + i * 256;
    float a = h2[(size_t)blk * EE + e];
    vals[i] = a; s1 += a; s2 += a * a;
  }
#pragma unroll
  for (int off = 32; off; off >>= 1) { s1 += __shfl_down(s1, off); s2 += __shfl_down(s2, off); }
  int wv = threadIdx.x >> 6;
  if ((threadIdx.x & 63) == 0) { red[wv] = s1; red[4 + wv] = s2; }
  __syncthreads();
  float t1 = red[0] + red[1] + red[2] + red[3];
  float t2 = red[4] + red[5] + red[6] + red[7];
  float mean = t1 * (1.f / 1024.f);
  float var = t2 * (1.f / 1024.f) - mean * mean;
  float ninv = rsqrtf(var + 1e-5f);
#pragma unroll
  for (int i = 0; i < 4; i++) {
    int e = threadIdx.x + i * 256;
    h3[(size_t)blk * EE + e] = f2bf((vals[i] - mean) * ninv * g2[e] + be2[e]);
  }
}

// ---------------- h3 (B,S,E) bf16 -> out (B,E,S) f32 ----------------
__global__ __launch_bounds__(256) void transpose_out(const short* __restrict__ h3, float* __restrict__ outp) {
  __shared__ short tile[64 * 65];
  int b = blockIdx.z;
  int e0 = blockIdx.y * 64;
  int s0 = blockIdx.x * 64;
  int tx = threadIdx.x & 63;
  int ty = threadIdx.x >> 6;
#pragma unroll
  for (int i = 0; i < 16; i++) {
    int r = ty + i * 4;
    int s = s0 + r;
    if (s < SS) tile[r * 65 + tx] = h3[((size_t)b * SS + s) * EE + e0 + tx];
  }
  __syncthreads();
#pragma unroll
  for (int i = 0; i < 16; i++) {
    int c = ty + i * 4;
    int s = s0 + tx;
    if (s < SS) outp[((size_t)b * EE + e0 + c) * SS + s] = bf2f(tile[tx * 65 + c]);
  }
}

// ---------------- workspace layout (~191 MB) ----------------
// slotA: xb -> h1 -> h3 (liveness disjoint); pad rows memset to 0 once.
// slotB: qkv (100.7 MB) + k1ib (at +100.7 MB) -> mid (134.2 MB, full-M)
// h2 (f32, 16000x1024 = exactly out_size) lives in d_out, consumed by ln2
// before transpose_out overwrites d_out.
#define ALIGN_UP(x) (((x) + 255) & ~(size_t)255)
static const size_t SZ_SLOTA = (size_t)MPAD * EE * 2;       // 33.55 MB
static const size_t SZ_QKV   = (size_t)MPAD * QKV_N * 2;    // 100.66 MB
static const size_t SZ_MID   = (size_t)MPAD * MLPD * 2;     // 134.22 MB
static const size_t SZ_WCAT  = (size_t)QKV_N * EE * 2;      // 6.29 MB
static const size_t SZ_W1B   = (size_t)MLPD * EE * 2;       // 8.39 MB
static const size_t SZ_W2B   = (size_t)EE * MLPD * 2;       // 8.39 MB
static const size_t SZ_QL    = (size_t)BB * HH * MLM * HDIM * 4;
static const size_t SZ_K2    = (size_t)BB * HH * 100 * 4;
static const size_t SZ_ST    = 512;

extern "C" void kernel_launch(void* const* d_in, const int* in_sizes, int n_in,
                              void* d_out, int out_size, void* d_ws, size_t ws_size,
                              hipStream_t stream) {
  const float* X   = (const float*)d_in[0];
  const float* Wq  = (const float*)d_in[1];
  const float* bq  = (const float*)d_in[2];
  const float* Wk  = (const float*)d_in[3];
  const float* bk  = (const float*)d_in[4];
  const float* Wv  = (const float*)d_in[5];
  const float* bv  = (const float*)d_in[6];
  const float* g1  = (const float*)d_in[7];
  const float* be1 = (const float*)d_in[8];
  const float* W1  = (const float*)d_in[9];
  const float* b1  = (const float*)d_in[10];
  const float* W2  = (const float*)d_in[11];
  const float* b2  = (const float*)d_in[12];
  const float* g2  = (const float*)d_in[13];
  const float* be2 = (const float*)d_in[14];

  char* ws = (char*)d_ws;
  size_t off = 0;
  char* slotA = ws + off; off += ALIGN_UP(SZ_SLOTA);
  char* slotB = ws + off; off += ALIGN_UP(SZ_MID);
  char* slotD = ws + off; off += ALIGN_UP(SZ_WCAT);
  short* W1b = (short*)(ws + off); off += ALIGN_UP(SZ_W1B);
  short* W2b = (short*)(ws + off); off += ALIGN_UP(SZ_W2B);

  short* xb   = (short*)slotA;
  short* h1   = (short*)slotA;
  short* h3   = (short*)slotA;
  short* qkv  = (short*)slotB;
  short* mid  = (short*)slotB;
  float* k1ib = (float*)(slotB + ALIGN_UP(SZ_QKV));
  short* Wcat = (short*)slotD;
  size_t doff = 0;
  float* Qlm  = (float*)(slotD + doff); doff += ALIGN_UP(SZ_QL);
  float* Klm  = (float*)(slotD + doff); doff += ALIGN_UP(SZ_QL);
  float* k2b  = (float*)(slotD + doff); doff += ALIGN_UP(SZ_K2);
  float* cmaxb= (float*)(slotD + doff); doff += ALIGN_UP(SZ_ST);
  float* rmaxb= (float*)(slotD + doff); doff += ALIGN_UP(SZ_ST);
  float* invb = (float*)(slotD + doff); doff += ALIGN_UP(SZ_K2);
  float* kvb  = (float*)(slotD + doff); doff += ALIGN_UP(SZ_QL);
  float* h2c  = (float*)d_out;   // exactly 16000*1024*4 bytes
  (void)ws_size; (void)in_sizes; (void)n_in; (void)out_size;

  // 0. zero slotA pad rows (so h1 pad rows are 0, not uninitialized bits)
  hipMemsetAsync(slotA + (size_t)BB * SS * EE * 2, 0,
                 (size_t)(MPAD - BB * SS) * EE * 2, stream);
  // 1. transpose/cast X
  transpose_x<<<dim3(63, 32, BB), dim3(32, 8), 0, stream>>>(X, xb);
  // 2. weight casts f32 -> bf16
  cast_f2b<<<2048, 256, 0, stream>>>(Wq, Wcat,             EE * EE);
  cast_f2b<<<2048, 256, 0, stream>>>(Wk, Wcat + EE * EE,   EE * EE);
  cast_f2b<<<2048, 256, 0, stream>>>(Wv, Wcat + 2*EE*EE,   EE * EE);
  cast_f2b<<<4096, 256, 0, stream>>>(W1, W1b, MLPD * EE);
  cast_f2b<<<4096, 256, 0, stream>>>(W2, W2b, EE * MLPD);
  // 3. QKV projection GEMM (Mpad=16384, N=3072, K=1024): 64x12 tiles
  gemm256<<<64 * 12, 512, 0, stream>>>(xb, Wcat, qkv, EE, QKV_N, 0, MPAD, bq, bk, bv);
  // 4. landmarks
  landmarks<<<dim3(BB * HH * MLM, 2), 64, 0, stream>>>(qkv, Qlm, Klm);
  // 5. k2 + stats
  k2stats<<<BB * HH, 128, 0, stream>>>(Qlm, Klm, k2b, cmaxb, rmaxb);
  // 6. iterative inverse
  invk<<<BB * HH, 128, 0, stream>>>(k2b, cmaxb, rmaxb, invb);
  // 7. k1 @ inv
  k1inv_kernel<<<dim3(125, BB), 256, 0, stream>>>(qkv, Klm, invb, k1ib);
  // 8. k3 @ V
  k3v_kernel<<<BB * HH, 256, 0, stream>>>(qkv, Qlm, kvb);
  // 9. attn + LN1
  attn_ln1<<<BB * SS, 256, 0, stream>>>(k1ib, kvb, g1, be1, h1);
  // 10. MLP1 (full M, 64x16 tiles), GELU epilogue -> mid (overwrites qkv+k1ib)
  gemm256<<<64 * 16, 512, 0, stream>>>(h1, W1b, mid, EE, MLPD, 1, MPAD, b1, nullptr, nullptr);
  // 11. MLP2 (full M, 64x4 tiles), f32 out into d_out, store-guarded to 16000 rows
  gemm256<<<64 * 4, 512, 0, stream>>>(mid, W2b, h2c, MLPD, EE, 2, BB * SS, b2, nullptr, nullptr);
  // 12. LN2: d_out(f32) -> h3(bf16, slotA)
  ln2_kernel<<<BB * SS, 256, 0, stream>>>(h2c, g2, be2, h3);
  // 13. transpose to (B,E,S) f32
  transpose_out<<<dim3(32, 16, BB), 256, 0, stream>>>(h3, (float*)d_out);
}

// Round 3
// 999.438 us; speedup vs baseline: 1.1726x; 1.1726x over previous
//
#include <hip/hip_runtime.h>
#include <cmath>
#include <cstdint>
#include <cstddef>

#define BB 8
#define EE 1024
#define SS 2000
#define HH 16
#define HDIM 64
#define MLM 10
#define MLPD 4096
#define QKV_N 3072
#define MPAD 16384  // 64*256 padded row count: every gemm grid divisible by 8 XCDs
#define QK_SCALE 0.35355339059327373f

typedef __attribute__((ext_vector_type(8))) short short8v;
typedef __attribute__((ext_vector_type(4))) float f32x4;

static __device__ __forceinline__ short f2bf(float x) {
  unsigned u = __builtin_bit_cast(unsigned, x);
  unsigned r = (u + 0x7fffu + ((u >> 16) & 1u)) >> 16;
  return (short)(unsigned short)r;
}
static __device__ __forceinline__ float bf2f(short x) {
  unsigned u = ((unsigned)(unsigned short)x) << 16;
  return __builtin_bit_cast(float, u);
}

// async global->LDS, 16B per lane; LDS dest is wave-uniform base + lane*16
static __device__ __forceinline__ void load_lds16(const short* g, short* l) {
  __builtin_amdgcn_global_load_lds(
      (const __attribute__((address_space(1))) void*)g,
      (__attribute__((address_space(3))) void*)l, 16, 0, 0);
}

// ---------------- X (B,E,S) f32 -> xb (B,S,E) bf16 ----------------
__global__ __launch_bounds__(256) void transpose_x(const float* __restrict__ X, short* __restrict__ xb) {
  __shared__ float tile[32][33];
  int b = blockIdx.z;
  int e0 = blockIdx.y * 32;
  int s0 = blockIdx.x * 32;
  int tx = threadIdx.x;      // 0..31
  int ty = threadIdx.y;      // 0..7
#pragma unroll
  for (int i = 0; i < 32; i += 8) {
    int e = e0 + ty + i, s = s0 + tx;
    tile[ty + i][tx] = (s < SS) ? X[((size_t)b * EE + e) * SS + s] : 0.f;
  }
  __syncthreads();
#pragma unroll
  for (int i = 0; i < 32; i += 8) {
    int s = s0 + ty + i, e = e0 + tx;
    if (s < SS) xb[((size_t)b * SS + s) * EE + e] = f2bf(tile[tx][ty + i]);
  }
}

// ---------------- f32 -> bf16 cast ----------------
__global__ __launch_bounds__(256) void cast_f2b(const float* __restrict__ src, short* __restrict__ dst, int n) {
  int i = blockIdx.x * 256 + threadIdx.x;
  int stride = gridDim.x * 256;
  for (; i < n; i += stride) dst[i] = f2bf(src[i]);
}

// =====================================================================
// 256x256xBK=64 8-phase bf16 GEMM, row-major LDS + st_16x32 XOR swizzle.
// C[m,n] = sum_k A[m,k]*Bm[n,k]  (both operands row-major [out][K])
// 8 waves (512 thr): wave (wm,wn) owns a 128x64 output sub-tile.
// LDS 128 KiB: 2 dbuf x {A,B} x {k-half} x 16 KiB region = [256 rows][64B].
// Swizzle (m201 st_16x32): 16B-slot ^= ((row>>3)&1)<<1, applied BOTH sides:
//  - staging: linear LDS dest (thread t -> row t>>2, slot t&3); the GLOBAL
//    source slot is pre-XOR'd (stays within the row's 64B -> coalescing of
//    16x64B segments per instruction preserved, same as the 285us r1 code).
//  - ds_read: slot' = quad ^ ((lm>>3)<<1)  (retrieves global slot quad).
// T3/T4: 1 half-tile (2x gload_lds) staged per phase; vmcnt(6) at phases
// 4 and 8 only (3 half-tiles in flight); last iteration peeled (drain).
// T5: setprio(1) around each 16-MFMA cluster.
// XCD map: xcd=bid&7 owns an 8-m-tile slice (A-slice ~4MB L2-resident),
// sweeps m fastest then n (B fetched once per XCD): FETCH measured ~optimal.
// =====================================================================
__global__ __launch_bounds__(512, 2) void gemm256(
    const short* __restrict__ A, const short* __restrict__ Bm, void* __restrict__ Cv,
    int K, int N, int mode, int Mstore,
    const float* __restrict__ p0, const float* __restrict__ p1, const float* __restrict__ p2)
{
  __shared__ __align__(16) short lds[65536];  // 128 KiB
  const int tid = threadIdx.x;

  // ---- XCD-aware tile mapping: grid = NT_N * 64, NT_M = 64 ----
  const int xcd = blockIdx.x & 7;
  const int idx = blockIdx.x >> 3;
  const int m0 = (((xcd << 3) | (idx & 7))) << 8;  // 64 m-tiles, 8 per XCD
  const int n0 = (idx >> 3) << 8;

  const int lane = tid & 63, wv = tid >> 6;
  const int wm = wv >> 2, wn = wv & 3;          // 2 x 4 wave grid
  const int lm = lane & 15, quad = lane >> 4;
  const int swz = ((lm >> 3) & 1) << 1;         // st_16x32 row-parity XOR
  // row-major read offsets (shorts): row*32 + swizzled 16B-slot*8
  const int aoff = (wm * 128 + lm) * 32 + ((quad ^ swz) << 3);
  const int boff = (wn * 64  + lm) * 32 + ((quad ^ swz) << 3);

  // staging: thread t writes LDS row t>>2, slot t&3 (linear, wave-uniform+lane*16);
  // global source slot pre-XOR'd by the same involution (row parity = (t>>5)&1)
  const int srow = tid >> 2;
  const int ssl  = ((tid & 3) ^ (((tid >> 5) & 1) << 1)) << 3;  // shorts
  const short* Ag = A + (size_t)(m0 + srow) * K + ssl;
  const short* Bg = Bm + (size_t)(n0 + srow) * K + ssl;
  const int wofs = wv << 9;                     // wave-uniform LDS chunk (shorts)

  f32x4 acc[8][4];
#pragma unroll
  for (int i = 0; i < 8; i++)
#pragma unroll
    for (int j = 0; j < 4; j++) acc[i][j] = (f32x4){0.f, 0.f, 0.f, 0.f};
  short8v afr[8], bfr[4];

// region(buf,op,kh) = 8192-short (16 KiB) block = [256 rows][32 shorts]
#define RGN(buf, op, kh) (&lds[((((buf)*2 + (op)) * 2 + (kh)) << 13)])
#define STG(op, buf, kh, kt) do {                                          \
    const short* gp_ = ((op) ? Bg : Ag) + ((kt) * 64 + (kh) * 32);         \
    short* lp_ = RGN(buf, op, kh) + wofs;                                  \
    load_lds16(gp_, lp_);                                                  \
    load_lds16(gp_ + (size_t)128 * K, lp_ + 4096);                         \
  } while (0)
#define LDA(buf, kh) do {                                                  \
    const short* r_ = RGN(buf, 0, kh) + aoff;                              \
    _Pragma("unroll") for (int i_ = 0; i_ < 8; ++i_)                       \
      afr[i_] = *(const short8v*)(r_ + i_ * 512);                          \
  } while (0)
#define LDB(buf, kh, jb) do {                                              \
    const short* r_ = RGN(buf, 1, kh) + boff;                              \
    bfr[jb]     = *(const short8v*)(r_ + (jb) * 512);                      \
    bfr[(jb)+1] = *(const short8v*)(r_ + ((jb)+1) * 512);                  \
  } while (0)
#define MM(jb) do {                                                        \
    __builtin_amdgcn_s_setprio(1);                                         \
    _Pragma("unroll") for (int i_ = 0; i_ < 8; ++i_) {                     \
      acc[i_][jb]     = __builtin_amdgcn_mfma_f32_16x16x32_bf16(           \
          afr[i_], bfr[jb],     acc[i_][jb],     0, 0, 0);                 \
      acc[i_][(jb)+1] = __builtin_amdgcn_mfma_f32_16x16x32_bf16(           \
          afr[i_], bfr[(jb)+1], acc[i_][(jb)+1], 0, 0, 0);                 \
    }                                                                      \
    __builtin_amdgcn_s_setprio(0);                                         \
  } while (0)
#define SBAR() do {                                                        \
    __builtin_amdgcn_sched_barrier(0);                                     \
    __builtin_amdgcn_s_barrier();                                          \
    __builtin_amdgcn_sched_barrier(0);                                     \
  } while (0)
#define WAITV(n) asm volatile("s_waitcnt vmcnt(" #n ")" ::: "memory")

// One iteration = 2 K-tiles (2it->buf0 phases 1-4, 2it+1->buf1 phases 5-8).
// Stage ledger (each stage >= 1 barrier after its region's last read):
//  P1: buf1.B.k1 tile 2it+1 | P2: buf0.A.k0 t+2 | P3: buf0.B.k0 | P4: buf0.A.k1
//  P5: buf0.B.k1 | P6: buf1.A.k0 t+3 | P7: buf1.B.k0 | P8: buf1.A.k1
// vmcnt(6)@P4 -> buf1 tile 2it+1 fully resident; @P8 -> buf0 tile 2it+2.
#define ITER(it, LAST) do {                                                              \
    LDB(0,0,0); LDA(0,0); STG(1,1,1, 2*(it)+1);                   SBAR(); MM(0); SBAR(); \
    LDB(0,0,2);           if (!(LAST)) STG(0,0,0, 2*(it)+2);      SBAR(); MM(2); SBAR(); \
    LDB(0,1,0); LDA(0,1); if (!(LAST)) STG(1,0,0, 2*(it)+2);      SBAR(); MM(0); SBAR(); \
    LDB(0,1,2);           if (!(LAST)) { STG(0,0,1, 2*(it)+2); WAITV(6); }               \
                          else         { WAITV(0); }              SBAR(); MM(2); SBAR(); \
    LDB(1,0,0); LDA(1,0); if (!(LAST)) STG(1,0,1, 2*(it)+2);      SBAR(); MM(0); SBAR(); \
    LDB(1,0,2);           if (!(LAST)) STG(0,1,0, 2*(it)+3);      SBAR(); MM(2); SBAR(); \
    LDB(1,1,0); LDA(1,1); if (!(LAST)) STG(1,1,0, 2*(it)+3);      SBAR(); MM(0); SBAR(); \
    LDB(1,1,2);           if (!(LAST)) { STG(0,1,1, 2*(it)+3); WAITV(6); }               \
                                                                  SBAR(); MM(2); SBAR(); \
  } while (0)

  const int NI = K >> 7;  // iterations (2 K-tiles each)
  // prologue: tile0 full -> buf0; tile1 {A.k0,B.k0,A.k1} -> buf1 (B.k1 at P1)
  STG(0,0,0, 0); STG(1,0,0, 0); STG(0,0,1, 0); STG(1,0,1, 0);
  STG(0,1,0, 1); STG(1,1,0, 1); STG(0,1,1, 1);
  WAITV(6);  // retire tile0's 8 loads; tile1's 6 stay in flight
  SBAR();

  for (int it = 0; it < NI - 1; ++it) ITER(it, 0);
  ITER(NI - 1, 1);

  // ---- epilogue ----
  const int crow0 = m0 + wm * 128 + quad * 4;
  const int ccol0 = n0 + wn * 64 + lm;
#pragma unroll
  for (int j = 0; j < 4; ++j) {
    const int col = ccol0 + j * 16;
    float bias, scl = 1.f;
    if (mode == 0) {
      if (col < 1024)      { bias = p0[col];        scl = QK_SCALE; }
      else if (col < 2048) { bias = p1[col - 1024]; scl = QK_SCALE; }
      else                 { bias = p2[col - 2048]; }
    } else {
      bias = p0[col];
    }
#pragma unroll
    for (int i = 0; i < 8; ++i) {
#pragma unroll
      for (int r = 0; r < 4; ++r) {
        const int row = crow0 + i * 16 + r;
        if (row < Mstore) {
          float v = acc[i][j][r] + bias;
          if (mode == 0)      v *= scl;
          else if (mode == 1) v = 0.5f * v * (1.f + erff(v * 0.70710678118f));
          if (mode == 2) ((float*)Cv)[(size_t)row * N + col] = v;
          else           ((short*)Cv)[(size_t)row * N + col] = f2bf(v);
        }
      }
    }
  }
#undef RGN
#undef STG
#undef LDA
#undef LDB
#undef MM
#undef SBAR
#undef WAITV
#undef ITER
}

// ---------------- landmarks: mean over 200-row segments ----------------
__global__ __launch_bounds__(64) void landmarks(const short* __restrict__ QKV, float* __restrict__ Ql, float* __restrict__ Kl) {
  int d = threadIdx.x;
  int bhm = blockIdx.x;
  int part = blockIdx.y;
  int b = bhm / (HH * MLM);
  int h = (bhm / MLM) % HH;
  int m = bhm % MLM;
  const short* src = QKV + (part ? 1024 : 0);
  size_t base = ((size_t)(b * SS + m * 200)) * QKV_N + h * HDIM + d;
  float acc = 0.f;
  for (int i = 0; i < 200; i++) acc += bf2f(src[base + (size_t)i * QKV_N]);
  float* dst = part ? Kl : Ql;
  dst[((size_t)(b * HH + h) * MLM + m) * HDIM + d] = acc * (1.f / 200.f);
}

// ---------------- k2 = softmax(Ql Kl^T) + per-bh col-sum/row-sum maxima ----------------
__global__ __launch_bounds__(128) void k2stats(const float* __restrict__ Ql, const float* __restrict__ Kl,
                                               float* __restrict__ k2, float* __restrict__ cmax, float* __restrict__ rmax) {
  int bh = blockIdx.x;
  __shared__ float QlS[640], KlS[640], zz[100], k2s[100], cs[10], rs[10];
  for (int i = threadIdx.x; i < 640; i += 128) {
    QlS[i] = Ql[(size_t)bh * 640 + i];
    KlS[i] = Kl[(size_t)bh * 640 + i];
  }
  __syncthreads();
  if (threadIdx.x < 100) {
    int i = threadIdx.x / 10, j = threadIdx.x % 10;
    float z = 0.f;
    for (int d = 0; d < 64; d++) z += QlS[i * 64 + d] * KlS[j * 64 + d];
    zz[threadIdx.x] = z;
  }
  __syncthreads();
  if (threadIdx.x < 10) {
    int i = threadIdx.x;
    float mx = -1e30f;
    for (int j = 0; j < 10; j++) mx = fmaxf(mx, zz[i * 10 + j]);
    float s = 0.f, e[10];
    for (int j = 0; j < 10; j++) { e[j] = expf(zz[i * 10 + j] - mx); s += e[j]; }
    float inv = 1.f / s, rsum = 0.f;
    for (int j = 0; j < 10; j++) {
      float v = e[j] * inv;
      k2s[i * 10 + j] = v;
      k2[(size_t)bh * 100 + i * 10 + j] = v;
      rsum += v;
    }
    rs[i] = rsum;
  }
  __syncthreads();
  if (threadIdx.x < 10) {
    int j = threadIdx.x;
    float c = 0.f;
    for (int i = 0; i < 10; i++) c += k2s[i * 10 + j];
    cs[j] = c;
  }
  __syncthreads();
  if (threadIdx.x == 0) {
    float m1 = 0.f, m2 = 0.f;
    for (int j = 0; j < 10; j++) { m1 = fmaxf(m1, cs[j]); m2 = fmaxf(m2, rs[j]); }
    cmax[bh] = m1;
    rmax[bh] = m2;
  }
}

// ---------------- Newton-Schulz pseudo-inverse of k2 (10x10), 6 iters ----------------
__global__ __launch_bounds__(128) void invk(const float* __restrict__ k2, const float* __restrict__ cmax,
                                            const float* __restrict__ rmax, float* __restrict__ invo) {
  int bh = blockIdx.x;
  __shared__ float gsc;
  __shared__ float Km[100], Vm[100], KV[100], Ta[100], Tb[100];
  if (threadIdx.x == 0) {
    float mc = 0.f, mr = 0.f;
    for (int i = 0; i < 128; i++) { mc = fmaxf(mc, cmax[i]); mr = fmaxf(mr, rmax[i]); }
    gsc = 1.f / (mc * mr);
  }
  for (int i = threadIdx.x; i < 100; i += 128) Km[i] = k2[(size_t)bh * 100 + i];
  __syncthreads();
  int t = threadIdx.x;
  int i = t / 10, j = t % 10;
  bool act = t < 100;
  if (act) Vm[t] = Km[j * 10 + i] * gsc;
  __syncthreads();
  for (int it = 0; it < 6; it++) {
    if (act) { float a = 0.f; for (int k = 0; k < 10; k++) a += Km[i * 10 + k] * Vm[k * 10 + j]; KV[t] = a; }
    __syncthreads();
    if (act) Ta[t] = (i == j ? 7.f : 0.f) - KV[t];
    __syncthreads();
    if (act) { float a = 0.f; for (int k = 0; k < 10; k++) a += KV[i * 10 + k] * Ta[k * 10 + j]; Tb[t] = (i == j ? 15.f : 0.f) - a; }
    __syncthreads();
    if (act) { float a = 0.f; for (int k = 0; k < 10; k++) a += KV[i * 10 + k] * Tb[k * 10 + j]; Ta[t] = (i == j ? 13.f : 0.f) - a; }
    __syncthreads();
    if (act) { float a = 0.f; for (int k = 0; k < 10; k++) a += Vm[i * 10 + k] * Ta[k * 10 + j]; Tb[t] = 0.25f * a; }
    __syncthreads();
    if (act) Vm[t] = Tb[t];
    __syncthreads();
  }
  if (act) invo[(size_t)bh * 100 + t] = Vm[t];
}

// ---------------- k1inv[b,s,h,:] = softmax(Q·Kl^T) @ inv ----------------
__global__ __launch_bounds__(256) void k1inv_kernel(const short* __restrict__ QKV, const float* __restrict__ Kl,
                                                    const float* __restrict__ invg, float* __restrict__ k1inv) {
  int b = blockIdx.y;
  int s0 = blockIdx.x * 16;
  __shared__ float KlS[16 * 650];
  __shared__ float invS[16 * 101];
  for (int idx = threadIdx.x; idx < 16 * 640; idx += 256) {
    int h = idx / 640, r = idx % 640;
    KlS[h * 650 + r] = Kl[(size_t)(b * HH + h) * 640 + r];
  }
  for (int idx = threadIdx.x; idx < 1600; idx += 256) {
    int h = idx / 100, r = idx % 100;
    invS[h * 101 + r] = invg[(size_t)(b * HH + h) * 100 + r];
  }
  __syncthreads();
  int sl = threadIdx.x >> 4, h = threadIdx.x & 15;
  int s = s0 + sl;
  size_t qoff = (size_t)(b * SS + s) * QKV_N + h * HDIM;
  float z[10];
#pragma unroll
  for (int m = 0; m < 10; m++) z[m] = 0.f;
  for (int c = 0; c < 8; c++) {
    short8v qv = *(const short8v*)&QKV[qoff + c * 8];
    float qf[8];
#pragma unroll
    for (int jj = 0; jj < 8; jj++) qf[jj] = bf2f(qv[jj]);
#pragma unroll
    for (int m = 0; m < 10; m++) {
      const float* kl = &KlS[h * 650 + m * 64 + c * 8];
      float a = 0.f;
#pragma unroll
      for (int jj = 0; jj < 8; jj++) a += qf[jj] * kl[jj];
      z[m] += a;
    }
  }
  float mx = z[0];
#pragma unroll
  for (int m = 1; m < 10; m++) mx = fmaxf(mx, z[m]);
  float p[10], ssum = 0.f;
#pragma unroll
  for (int m = 0; m < 10; m++) { p[m] = expf(z[m] - mx); ssum += p[m]; }
  float rinv = 1.f / ssum;
  float* dst = &k1inv[((size_t)(b * SS + s) * HH + h) * MLM];
#pragma unroll
  for (int mm = 0; mm < 10; mm++) {
    float a = 0.f;
#pragma unroll
    for (int jjj = 0; jjj < 10; jjj++) a += p[jjj] * invS[h * 101 + jjj * 10 + mm];
    dst[mm] = a * rinv;
  }
}

// ---------------- kv[b,h,m,:] = softmax_s(Ql·K) @ V  (single-pass) ----------------
__global__ __launch_bounds__(256) void k3v_kernel(const short* __restrict__ QKV, const float* __restrict__ Qlg,
                                                  float* __restrict__ kvout) {
  int bh = blockIdx.x;
  int b = bh >> 4, h = bh & 15;
  __shared__ float Kt[64 * 65];
  __shared__ float Vt[64 * 65];
  __shared__ float eS[10 * 64];
  __shared__ float QlS[640];
  __shared__ float denS[10];
  int tid = threadIdx.x;
  int wave = tid >> 6, lane = tid & 63;
  for (int i = tid; i < 640; i += 256) QlS[i] = Qlg[(size_t)bh * 640 + i];
  float myden = 0.f;
  float accn[3] = {0.f, 0.f, 0.f};
  int rowi = tid >> 2;
  int d0 = (tid & 3) * 16;
  for (int s0 = 0; s0 < SS; s0 += 64) {
    __syncthreads();
    if (s0 + rowi < SS) {
      size_t base = (size_t)(b * SS + s0 + rowi) * QKV_N + h * HDIM + d0;
      short8v k0v = *(const short8v*)&QKV[base + 1024];
      short8v k1v = *(const short8v*)&QKV[base + 1024 + 8];
      short8v v0v = *(const short8v*)&QKV[base + 2048];
      short8v v1v = *(const short8v*)&QKV[base + 2048 + 8];
#pragma unroll
      for (int jj = 0; jj < 8; jj++) {
        Kt[rowi * 65 + d0 + jj]     = bf2f(k0v[jj]);
        Kt[rowi * 65 + d0 + 8 + jj] = bf2f(k1v[jj]);
        Vt[rowi * 65 + d0 + jj]     = bf2f(v0v[jj]);
        Vt[rowi * 65 + d0 + 8 + jj] = bf2f(v1v[jj]);
      }
    }
    __syncthreads();
    for (int mb = 0; mb < 12; mb += 4) {
      int m = mb + wave;
      if (m < 10) {
        float z = 0.f;
        const float* kr = &Kt[lane * 65];
        const float* ql = &QlS[m * 64];
        for (int d = 0; d < 64; d++) z += ql[d] * kr[d];
        eS[m * 64 + lane] = (s0 + lane < SS) ? expf(z) : 0.f;
      }
    }
    __syncthreads();
    if (tid < 10) {
      float a = 0.f;
      for (int slj = 0; slj < 64; slj++) a += eS[tid * 64 + slj];
      myden += a;
    }
#pragma unroll
    for (int ii = 0; ii < 3; ii++) {
      int idx = tid + ii * 256;
      if (idx < 640) {
        int m = idx >> 6, d = idx & 63;
        float a = 0.f;
        for (int slj = 0; slj < 64; slj++) a += eS[m * 64 + slj] * Vt[slj * 65 + d];
        accn[ii] += a;
      }
    }
  }
  if (tid < 10) denS[tid] = myden;
  __syncthreads();
#pragma unroll
  for (int ii = 0; ii < 3; ii++) {
    int idx = tid + ii * 256;
    if (idx < 640) {
      int m = idx >> 6;
      kvout[(size_t)bh * 640 + idx] = accn[ii] / denS[m];
    }
  }
}

// ---------------- attn row = k1inv row @ kv, then LayerNorm(g1,be1) -> bf16 ----------------
__global__ __launch_bounds__(256) void attn_ln1(const float* __restrict__ k1inv, const float* __restrict__ kvg,
                                                const float* __restrict__ g1, const float* __restrict__ be1,
                                                short* __restrict__ h1) {
  int blk = blockIdx.x;
  int b = blk / SS;
  __shared__ float pS[160];
  __shared__ float red[8];
  for (int i = threadIdx.x; i < 160; i += 256) pS[i] = k1inv[(size_t)blk * 160 + i];
  __syncthreads();
  float vals[4], s1 = 0.f, s2 = 0.f;
#pragma unroll
  for (int i = 0; i < 4; i++) {
    int e = threadIdx.x + i * 256;
    int h = e >> 6, d = e & 63;
    const float* kvp = &kvg[((size_t)(b * HH + h) * MLM) * HDIM + d];
    const float* pp = &pS[h * 10];
    float a = 0.f;
#pragma unroll
    for (int m = 0; m < 10; m++) a += pp[m] * kvp[m * 64];
    vals[i] = a; s1 += a; s2 += a * a;
  }
#pragma unroll
  for (int off = 32; off; off >>= 1) { s1 += __shfl_down(s1, off); s2 += __shfl_down(s2, off); }
  int wv = threadIdx.x >> 6;
  if ((threadIdx.x & 63) == 0) { red[wv] = s1; red[4 + wv] = s2; }
  __syncthreads();
  float t1 = red[0] + red[1] + red[2] + red[3];
  float t2 = red[4] + red[5] + red[6] + red[7];
  float mean = t1 * (1.f / 1024.f);
  float var = t2 * (1.f / 1024.f) - mean * mean;
  float ninv = rsqrtf(var + 1e-5f);
#pragma unroll
  for (int i = 0; i < 4; i++) {
    int e = threadIdx.x + i * 256;
    h1[(size_t)blk * EE + e] = f2bf((vals[i] - mean) * ninv * g1[e] + be1[e]);
  }
}

// ---------------- LayerNorm(g2,be2) on f32 rows -> bf16 ----------------
__global__ __launch_bounds__(256) void ln2_kernel(const float* __restrict__ h2, const float* __restrict__ g2,
                                                  const float* __restrict__ be2, short* __restrict__ h3) {
  int blk = blockIdx.x;
  __shared__ float red[8];
  float vals[4], s1 = 0.f, s2 = 0.f;
#pragma unroll
  for (int i = 0; i < 4; i++) {
    int e = threadIdx.x + i * 256;
    float a = h2[(size_t)blk * EE + e];
    vals[i] = a; s1 += a; s2 += a * a;
  }
#pragma unroll
  for (int off = 32; off; off >>= 1) { s1 += __shfl_down(s1, off); s2 += __shfl_down(s2, off); }
  int wv = threadIdx.x >> 6;
  if ((threadIdx.x & 63) == 0) { red[wv] = s1; red[4 + wv] = s2; }
  __syncthreads();
  float t1 = red[0] + red[1] + red[2] + red[3];
  float t2 = red[4] + red[5] + red[6] + red[7];
  float mean = t1 * (1.f / 1024.f);
  float var = t2 * (1.f / 1024.f) - mean * mean;
  float ninv = rsqrtf(var + 1e-5f);
#pragma unroll
  for (int i = 0; i < 4; i++) {
    int e = threadIdx.x + i * 256;
    h3[(size_t)blk * EE + e] = f2bf((vals[i] - mean) * ninv * g2[e] + be2[e]);
  }
}

// ---------------- h3 (B,S,E) bf16 -> out (B,E,S) f32 ----------------
__global__ __launch_bounds__(256) void transpose_out(const short* __restrict__ h3, float* __restrict__ outp) {
  __shared__ short tile[64 * 65];
  int b = blockIdx.z;
  int e0 = blockIdx.y * 64;
  int s0 = blockIdx.x * 64;
  int tx = threadIdx.x & 63;
  int ty = threadIdx.x >> 6;
#pragma unroll
  for (int i = 0; i < 16; i++) {
    int r = ty + i * 4;
    int s = s0 + r;
    if (s < SS) tile[r * 65 + tx] = h3[((size_t)b * SS + s) * EE + e0 + tx];
  }
  __syncthreads();
#pragma unroll
  for (int i = 0; i < 16; i++) {
    int c = ty + i * 4;
    int s = s0 + tx;
    if (s < SS) outp[((size_t)b * EE + e0 + c) * SS + s] = bf2f(tile[tx * 65 + c]);
  }
}

// ---------------- workspace layout (~191 MB) ----------------
// slotA: xb -> h1 -> h3 (liveness disjoint); pad rows memset to 0 once.
// slotB: qkv (100.7 MB) + k1ib (at +100.7 MB) -> mid (134.2 MB, full-M)
// h2 (f32, 16000x1024 = exactly out_size) lives in d_out, consumed by ln2
// before transpose_out overwrites d_out.
#define ALIGN_UP(x) (((x) + 255) & ~(size_t)255)
static const size_t SZ_SLOTA = (size_t)MPAD * EE * 2;       // 33.55 MB
static const size_t SZ_QKV   = (size_t)MPAD * QKV_N * 2;    // 100.66 MB
static const size_t SZ_MID   = (size_t)MPAD * MLPD * 2;     // 134.22 MB
static const size_t SZ_WCAT  = (size_t)QKV_N * EE * 2;      // 6.29 MB
static const size_t SZ_W1B   = (size_t)MLPD * EE * 2;       // 8.39 MB
static const size_t SZ_W2B   = (size_t)EE * MLPD * 2;       // 8.39 MB
static const size_t SZ_QL    = (size_t)BB * HH * MLM * HDIM * 4;
static const size_t SZ_K2    = (size_t)BB * HH * 100 * 4;
static const size_t SZ_ST    = 512;

extern "C" void kernel_launch(void* const* d_in, const int* in_sizes, int n_in,
                              void* d_out, int out_size, void* d_ws, size_t ws_size,
                              hipStream_t stream) {
  const float* X   = (const float*)d_in[0];
  const float* Wq  = (const float*)d_in[1];
  const float* bq  = (const float*)d_in[2];
  const float* Wk  = (const float*)d_in[3];
  const float* bk  = (const float*)d_in[4];
  const float* Wv  = (const float*)d_in[5];
  const float* bv  = (const float*)d_in[6];
  const float* g1  = (const float*)d_in[7];
  const float* be1 = (const float*)d_in[8];
  const float* W1  = (const float*)d_in[9];
  const float* b1  = (const float*)d_in[10];
  const float* W2  = (const float*)d_in[11];
  const float* b2  = (const float*)d_in[12];
  const float* g2  = (const float*)d_in[13];
  const float* be2 = (const float*)d_in[14];

  char* ws = (char*)d_ws;
  size_t off = 0;
  char* slotA = ws + off; off += ALIGN_UP(SZ_SLOTA);
  char* slotB = ws + off; off += ALIGN_UP(SZ_MID);
  char* slotD = ws + off; off += ALIGN_UP(SZ_WCAT);
  short* W1b = (short*)(ws + off); off += ALIGN_UP(SZ_W1B);
  short* W2b = (short*)(ws + off); off += ALIGN_UP(SZ_W2B);

  short* xb   = (short*)slotA;
  short* h1   = (short*)slotA;
  short* h3   = (short*)slotA;
  short* qkv  = (short*)slotB;
  short* mid  = (short*)slotB;
  float* k1ib = (float*)(slotB + ALIGN_UP(SZ_QKV));
  short* Wcat = (short*)slotD;
  size_t doff = 0;
  float* Qlm  = (float*)(slotD + doff); doff += ALIGN_UP(SZ_QL);
  float* Klm  = (float*)(slotD + doff); doff += ALIGN_UP(SZ_QL);
  float* k2b  = (float*)(slotD + doff); doff += ALIGN_UP(SZ_K2);
  float* cmaxb= (float*)(slotD + doff); doff += ALIGN_UP(SZ_ST);
  float* rmaxb= (float*)(slotD + doff); doff += ALIGN_UP(SZ_ST);
  float* invb = (float*)(slotD + doff); doff += ALIGN_UP(SZ_K2);
  float* kvb  = (float*)(slotD + doff); doff += ALIGN_UP(SZ_QL);
  float* h2c  = (float*)d_out;   // exactly 16000*1024*4 bytes
  (void)ws_size; (void)in_sizes; (void)n_in; (void)out_size;

  // 0. zero slotA pad rows (so h1 pad rows are 0, not uninitialized bits)
  hipMemsetAsync(slotA + (size_t)BB * SS * EE * 2, 0,
                 (size_t)(MPAD - BB * SS) * EE * 2, stream);
  // 1. transpose/cast X
  transpose_x<<<dim3(63, 32, BB), dim3(32, 8), 0, stream>>>(X, xb);
  // 2. weight casts f32 -> bf16
  cast_f2b<<<2048, 256, 0, stream>>>(Wq, Wcat,             EE * EE);
  cast_f2b<<<2048, 256, 0, stream>>>(Wk, Wcat + EE * EE,   EE * EE);
  cast_f2b<<<2048, 256, 0, stream>>>(Wv, Wcat + 2*EE*EE,   EE * EE);
  cast_f2b<<<4096, 256, 0, stream>>>(W1, W1b, MLPD * EE);
  cast_f2b<<<4096, 256, 0, stream>>>(W2, W2b, EE * MLPD);
  // 3. QKV projection GEMM (Mpad=16384, N=3072, K=1024): 64x12 tiles
  gemm256<<<64 * 12, 512, 0, stream>>>(xb, Wcat, qkv, EE, QKV_N, 0, MPAD, bq, bk, bv);
  // 4. landmarks
  landmarks<<<dim3(BB * HH * MLM, 2), 64, 0, stream>>>(qkv, Qlm, Klm);
  // 5. k2 + stats
  k2stats<<<BB * HH, 128, 0, stream>>>(Qlm, Klm, k2b, cmaxb, rmaxb);
  // 6. iterative inverse
  invk<<<BB * HH, 128, 0, stream>>>(k2b, cmaxb, rmaxb, invb);
  // 7. k1 @ inv
  k1inv_kernel<<<dim3(125, BB), 256, 0, stream>>>(qkv, Klm, invb, k1ib);
  // 8. k3 @ V
  k3v_kernel<<<BB * HH, 256, 0, stream>>>(qkv, Qlm, kvb);
  // 9. attn + LN1
  attn_ln1<<<BB * SS, 256, 0, stream>>>(k1ib, kvb, g1, be1, h1);
  // 10. MLP1 (full M, 64x16 tiles), GELU epilogue -> mid (overwrites qkv+k1ib)
  gemm256<<<64 * 16, 512, 0, stream>>>(h1, W1b, mid, EE, MLPD, 1, MPAD, b1, nullptr, nullptr);
  // 11. MLP2 (full M, 64x4 tiles), f32 out into d_out, store-guarded to 16000 rows
  gemm256<<<64 * 4, 512, 0, stream>>>(mid, W2b, h2c, MLPD, EE, 2, BB * SS, b2, nullptr, nullptr);
  // 12. LN2: d_out(f32) -> h3(bf16, slotA)
  ln2_kernel<<<BB * SS, 256, 0, stream>>>(h2c, g2, be2, h3);
  // 13. transpose to (B,E,S) f32
  transpose_out<<<dim3(32, 16, BB), 256, 0, stream>>>(h3, (float*)d_out);
}

// Round 4
// 983.117 us; speedup vs baseline: 1.1921x; 1.0166x over previous
//
#include <hip/hip_runtime.h>
#include <cmath>
#include <cstdint>
#include <cstddef>

#define BB 8
#define EE 1024
#define SS 2000
#define HH 16
#define HDIM 64
#define MLM 10
#define MLPD 4096
#define QKV_N 3072
#define MPAD 16384  // 64*256 padded row count: every gemm grid divisible by 8 XCDs
#define QK_SCALE 0.35355339059327373f

typedef __attribute__((ext_vector_type(8))) short short8v;
typedef __attribute__((ext_vector_type(4))) float f32x4;

static __device__ __forceinline__ short f2bf(float x) {
  unsigned u = __builtin_bit_cast(unsigned, x);
  unsigned r = (u + 0x7fffu + ((u >> 16) & 1u)) >> 16;
  return (short)(unsigned short)r;
}
static __device__ __forceinline__ float bf2f(short x) {
  unsigned u = ((unsigned)(unsigned short)x) << 16;
  return __builtin_bit_cast(float, u);
}

// async global->LDS, 16B per lane; LDS dest is wave-uniform base + lane*16
static __device__ __forceinline__ void load_lds16(const short* g, short* l) {
  __builtin_amdgcn_global_load_lds(
      (const __attribute__((address_space(1))) void*)g,
      (__attribute__((address_space(3))) void*)l, 16, 0, 0);
}

// ---------------- X (B,E,S) f32 -> xb (B,S,E) bf16 ----------------
__global__ __launch_bounds__(256) void transpose_x(const float* __restrict__ X, short* __restrict__ xb) {
  __shared__ float tile[32][33];
  int b = blockIdx.z;
  int e0 = blockIdx.y * 32;
  int s0 = blockIdx.x * 32;
  int tx = threadIdx.x;      // 0..31
  int ty = threadIdx.y;      // 0..7
#pragma unroll
  for (int i = 0; i < 32; i += 8) {
    int e = e0 + ty + i, s = s0 + tx;
    tile[ty + i][tx] = (s < SS) ? X[((size_t)b * EE + e) * SS + s] : 0.f;
  }
  __syncthreads();
#pragma unroll
  for (int i = 0; i < 32; i += 8) {
    int s = s0 + ty + i, e = e0 + tx;
    if (s < SS) xb[((size_t)b * SS + s) * EE + e] = f2bf(tile[tx][ty + i]);
  }
}

// ---------------- f32 -> bf16 cast ----------------
__global__ __launch_bounds__(256) void cast_f2b(const float* __restrict__ src, short* __restrict__ dst, int n) {
  int i = blockIdx.x * 256 + threadIdx.x;
  int stride = gridDim.x * 256;
  for (; i < n; i += stride) dst[i] = f2bf(src[i]);
}

// =====================================================================
// 256x256xBK=64 8-phase bf16 GEMM, row-major LDS + st_16x32 XOR swizzle.
// C[m,n] = sum_k A[m,k]*Bm[n,k]  (both operands row-major [out][K])
// 8 waves (512 thr): wave (wm,wn) owns a 128x64 output sub-tile.
// LDS 128 KiB: 2 dbuf x {A,B} x {k-half} x 16 KiB region = [256 rows][64B].
// Swizzle: 16B-slot ^= ((row>>3)&1)<<1, applied BOTH sides (src + read);
// zero LDS bank conflicts (verified by PMC in r3).
// Barriers: RAW s_barrier with "memory" clobber ONLY — no sched_barrier(0).
// (r3 post-mortem: the sched_barrier(0) pins reproduced m141's 510-TF
// regression; the compiler must stay free to schedule across phases.)
// T3/T4: 1 half-tile (2x gload_lds) staged per phase; vmcnt(6) at phases
// 4 and 8 only (3 half-tiles in flight); last iteration peeled (drain).
// T5: setprio(1) around each 16-MFMA cluster.
// XCD map: xcd=bid&7 owns an 8-m-tile slice, sweeps m fastest then n.
// =====================================================================
__global__ __launch_bounds__(512, 2) void gemm256(
    const short* __restrict__ A, const short* __restrict__ Bm, void* __restrict__ Cv,
    int K, int N, int mode, int Mstore,
    const float* __restrict__ p0, const float* __restrict__ p1, const float* __restrict__ p2)
{
  __shared__ __align__(16) short lds[65536];  // 128 KiB
  const int tid = threadIdx.x;

  // ---- XCD-aware tile mapping: grid = NT_N * 64, NT_M = 64 ----
  const int xcd = blockIdx.x & 7;
  const int idx = blockIdx.x >> 3;
  const int m0 = (((xcd << 3) | (idx & 7))) << 8;  // 64 m-tiles, 8 per XCD
  const int n0 = (idx >> 3) << 8;

  const int lane = tid & 63, wv = tid >> 6;
  const int wm = wv >> 2, wn = wv & 3;          // 2 x 4 wave grid
  const int lm = lane & 15, quad = lane >> 4;
  const int swz = ((lm >> 3) & 1) << 1;         // st_16x32 row-parity XOR
  // row-major read offsets (shorts): row*32 + swizzled 16B-slot*8
  const int aoff = (wm * 128 + lm) * 32 + ((quad ^ swz) << 3);
  const int boff = (wn * 64  + lm) * 32 + ((quad ^ swz) << 3);

  // staging: thread t writes LDS row t>>2, slot t&3 (linear, wave-uniform+lane*16);
  // global source slot pre-XOR'd by the same involution (row parity = (t>>5)&1)
  const int srow = tid >> 2;
  const int ssl  = ((tid & 3) ^ (((tid >> 5) & 1) << 1)) << 3;  // shorts
  const short* Ag = A + (size_t)(m0 + srow) * K + ssl;
  const short* Bg = Bm + (size_t)(n0 + srow) * K + ssl;
  const int wofs = wv << 9;                     // wave-uniform LDS chunk (shorts)

  f32x4 acc[8][4];
#pragma unroll
  for (int i = 0; i < 8; i++)
#pragma unroll
    for (int j = 0; j < 4; j++) acc[i][j] = (f32x4){0.f, 0.f, 0.f, 0.f};
  short8v afr[8], bfr[4];

// region(buf,op,kh) = 8192-short (16 KiB) block = [256 rows][32 shorts]
#define RGN(buf, op, kh) (&lds[((((buf)*2 + (op)) * 2 + (kh)) << 13)])
#define STG(op, buf, kh, kt) do {                                          \
    const short* gp_ = ((op) ? Bg : Ag) + ((kt) * 64 + (kh) * 32);         \
    short* lp_ = RGN(buf, op, kh) + wofs;                                  \
    load_lds16(gp_, lp_);                                                  \
    load_lds16(gp_ + (size_t)128 * K, lp_ + 4096);                         \
  } while (0)
#define LDA(buf, kh) do {                                                  \
    const short* r_ = RGN(buf, 0, kh) + aoff;                              \
    _Pragma("unroll") for (int i_ = 0; i_ < 8; ++i_)                       \
      afr[i_] = *(const short8v*)(r_ + i_ * 512);                          \
  } while (0)
#define LDB(buf, kh, jb) do {                                              \
    const short* r_ = RGN(buf, 1, kh) + boff;                              \
    bfr[jb]     = *(const short8v*)(r_ + (jb) * 512);                      \
    bfr[(jb)+1] = *(const short8v*)(r_ + ((jb)+1) * 512);                  \
  } while (0)
#define MM(jb) do {                                                        \
    __builtin_amdgcn_s_setprio(1);                                         \
    _Pragma("unroll") for (int i_ = 0; i_ < 8; ++i_) {                     \
      acc[i_][jb]     = __builtin_amdgcn_mfma_f32_16x16x32_bf16(           \
          afr[i_], bfr[jb],     acc[i_][jb],     0, 0, 0);                 \
      acc[i_][(jb)+1] = __builtin_amdgcn_mfma_f32_16x16x32_bf16(           \
          afr[i_], bfr[(jb)+1], acc[i_][(jb)+1], 0, 0, 0);                 \
    }                                                                      \
    __builtin_amdgcn_s_setprio(0);                                         \
  } while (0)
#define SBAR() asm volatile("s_barrier" ::: "memory")
#define WAITV(n) asm volatile("s_waitcnt vmcnt(" #n ")" ::: "memory")

// One iteration = 2 K-tiles (2it->buf0 phases 1-4, 2it+1->buf1 phases 5-8).
// Stage ledger (each stage >= 1 barrier after its region's last read):
//  P1: buf1.B.k1 tile 2it+1 | P2: buf0.A.k0 t+2 | P3: buf0.B.k0 | P4: buf0.A.k1
//  P5: buf0.B.k1 | P6: buf1.A.k0 t+3 | P7: buf1.B.k0 | P8: buf1.A.k1
// vmcnt(6)@P4 -> buf1 tile 2it+1 fully resident; @P8 -> buf0 tile 2it+2.
#define ITER(it, LAST) do {                                                              \
    LDB(0,0,0); LDA(0,0); STG(1,1,1, 2*(it)+1);                   SBAR(); MM(0); SBAR(); \
    LDB(0,0,2);           if (!(LAST)) STG(0,0,0, 2*(it)+2);      SBAR(); MM(2); SBAR(); \
    LDB(0,1,0); LDA(0,1); if (!(LAST)) STG(1,0,0, 2*(it)+2);      SBAR(); MM(0); SBAR(); \
    LDB(0,1,2);           if (!(LAST)) { STG(0,0,1, 2*(it)+2); WAITV(6); }               \
                          else         { WAITV(0); }              SBAR(); MM(2); SBAR(); \
    LDB(1,0,0); LDA(1,0); if (!(LAST)) STG(1,0,1, 2*(it)+2);      SBAR(); MM(0); SBAR(); \
    LDB(1,0,2);           if (!(LAST)) STG(0,1,0, 2*(it)+3);      SBAR(); MM(2); SBAR(); \
    LDB(1,1,0); LDA(1,1); if (!(LAST)) STG(1,1,0, 2*(it)+3);      SBAR(); MM(0); SBAR(); \
    LDB(1,1,2);           if (!(LAST)) { STG(0,1,1, 2*(it)+3); WAITV(6); }               \
                                                                  SBAR(); MM(2); SBAR(); \
  } while (0)

  const int NI = K >> 7;  // iterations (2 K-tiles each)
  // prologue: tile0 full -> buf0; tile1 {A.k0,B.k0,A.k1} -> buf1 (B.k1 at P1)
  STG(0,0,0, 0); STG(1,0,0, 0); STG(0,0,1, 0); STG(1,0,1, 0);
  STG(0,1,0, 1); STG(1,1,0, 1); STG(0,1,1, 1);
  WAITV(6);  // retire tile0's 8 loads; tile1's 6 stay in flight
  SBAR();

  for (int it = 0; it < NI - 1; ++it) ITER(it, 0);
  ITER(NI - 1, 1);

  // ---- epilogue ----
  const int crow0 = m0 + wm * 128 + quad * 4;
  const int ccol0 = n0 + wn * 64 + lm;
#pragma unroll
  for (int j = 0; j < 4; ++j) {
    const int col = ccol0 + j * 16;
    float bias, scl = 1.f;
    if (mode == 0) {
      if (col < 1024)      { bias = p0[col];        scl = QK_SCALE; }
      else if (col < 2048) { bias = p1[col - 1024]; scl = QK_SCALE; }
      else                 { bias = p2[col - 2048]; }
    } else {
      bias = p0[col];
    }
#pragma unroll
    for (int i = 0; i < 8; ++i) {
#pragma unroll
      for (int r = 0; r < 4; ++r) {
        const int row = crow0 + i * 16 + r;
        if (row < Mstore) {
          float v = acc[i][j][r] + bias;
          if (mode == 0)      v *= scl;
          else if (mode == 1) v = 0.5f * v * (1.f + erff(v * 0.70710678118f));
          if (mode == 2) ((float*)Cv)[(size_t)row * N + col] = v;
          else           ((short*)Cv)[(size_t)row * N + col] = f2bf(v);
        }
      }
    }
  }
#undef RGN
#undef STG
#undef LDA
#undef LDB
#undef MM
#undef SBAR
#undef WAITV
#undef ITER
}

// ---------------- landmarks: mean over 200-row segments ----------------
__global__ __launch_bounds__(64) void landmarks(const short* __restrict__ QKV, float* __restrict__ Ql, float* __restrict__ Kl) {
  int d = threadIdx.x;
  int bhm = blockIdx.x;
  int part = blockIdx.y;
  int b = bhm / (HH * MLM);
  int h = (bhm / MLM) % HH;
  int m = bhm % MLM;
  const short* src = QKV + (part ? 1024 : 0);
  size_t base = ((size_t)(b * SS + m * 200)) * QKV_N + h * HDIM + d;
  float acc = 0.f;
  for (int i = 0; i < 200; i++) acc += bf2f(src[base + (size_t)i * QKV_N]);
  float* dst = part ? Kl : Ql;
  dst[((size_t)(b * HH + h) * MLM + m) * HDIM + d] = acc * (1.f / 200.f);
}

// ---------------- k2 = softmax(Ql Kl^T) + per-bh col-sum/row-sum maxima ----------------
__global__ __launch_bounds__(128) void k2stats(const float* __restrict__ Ql, const float* __restrict__ Kl,
                                               float* __restrict__ k2, float* __restrict__ cmax, float* __restrict__ rmax) {
  int bh = blockIdx.x;
  __shared__ float QlS[640], KlS[640], zz[100], k2s[100], cs[10], rs[10];
  for (int i = threadIdx.x; i < 640; i += 128) {
    QlS[i] = Ql[(size_t)bh * 640 + i];
    KlS[i] = Kl[(size_t)bh * 640 + i];
  }
  __syncthreads();
  if (threadIdx.x < 100) {
    int i = threadIdx.x / 10, j = threadIdx.x % 10;
    float z = 0.f;
    for (int d = 0; d < 64; d++) z += QlS[i * 64 + d] * KlS[j * 64 + d];
    zz[threadIdx.x] = z;
  }
  __syncthreads();
  if (threadIdx.x < 10) {
    int i = threadIdx.x;
    float mx = -1e30f;
    for (int j = 0; j < 10; j++) mx = fmaxf(mx, zz[i * 10 + j]);
    float s = 0.f, e[10];
    for (int j = 0; j < 10; j++) { e[j] = expf(zz[i * 10 + j] - mx); s += e[j]; }
    float inv = 1.f / s, rsum = 0.f;
    for (int j = 0; j < 10; j++) {
      float v = e[j] * inv;
      k2s[i * 10 + j] = v;
      k2[(size_t)bh * 100 + i * 10 + j] = v;
      rsum += v;
    }
    rs[i] = rsum;
  }
  __syncthreads();
  if (threadIdx.x < 10) {
    int j = threadIdx.x;
    float c = 0.f;
    for (int i = 0; i < 10; i++) c += k2s[i * 10 + j];
    cs[j] = c;
  }
  __syncthreads();
  if (threadIdx.x == 0) {
    float m1 = 0.f, m2 = 0.f;
    for (int j = 0; j < 10; j++) { m1 = fmaxf(m1, cs[j]); m2 = fmaxf(m2, rs[j]); }
    cmax[bh] = m1;
    rmax[bh] = m2;
  }
}

// ---------------- Newton-Schulz pseudo-inverse of k2 (10x10), 6 iters ----------------
__global__ __launch_bounds__(128) void invk(const float* __restrict__ k2, const float* __restrict__ cmax,
                                            const float* __restrict__ rmax, float* __restrict__ invo) {
  int bh = blockIdx.x;
  __shared__ float gsc;
  __shared__ float Km[100], Vm[100], KV[100], Ta[100], Tb[100];
  if (threadIdx.x == 0) {
    float mc = 0.f, mr = 0.f;
    for (int i = 0; i < 128; i++) { mc = fmaxf(mc, cmax[i]); mr = fmaxf(mr, rmax[i]); }
    gsc = 1.f / (mc * mr);
  }
  for (int i = threadIdx.x; i < 100; i += 128) Km[i] = k2[(size_t)bh * 100 + i];
  __syncthreads();
  int t = threadIdx.x;
  int i = t / 10, j = t % 10;
  bool act = t < 100;
  if (act) Vm[t] = Km[j * 10 + i] * gsc;
  __syncthreads();
  for (int it = 0; it < 6; it++) {
    if (act) { float a = 0.f; for (int k = 0; k < 10; k++) a += Km[i * 10 + k] * Vm[k * 10 + j]; KV[t] = a; }
    __syncthreads();
    if (act) Ta[t] = (i == j ? 7.f : 0.f) - KV[t];
    __syncthreads();
    if (act) { float a = 0.f; for (int k = 0; k < 10; k++) a += KV[i * 10 + k] * Ta[k * 10 + j]; Tb[t] = (i == j ? 15.f : 0.f) - a; }
    __syncthreads();
    if (act) { float a = 0.f; for (int k = 0; k < 10; k++) a += KV[i * 10 + k] * Tb[k * 10 + j]; Ta[t] = (i == j ? 13.f : 0.f) - a; }
    __syncthreads();
    if (act) { float a = 0.f; for (int k = 0; k < 10; k++) a += Vm[i * 10 + k] * Ta[k * 10 + j]; Tb[t] = 0.25f * a; }
    __syncthreads();
    if (act) Vm[t] = Tb[t];
    __syncthreads();
  }
  if (act) invo[(size_t)bh * 100 + t] = Vm[t];
}

// ---------------- k1inv[b,s,h,:] = softmax(Q·Kl^T) @ inv ----------------
__global__ __launch_bounds__(256) void k1inv_kernel(const short* __restrict__ QKV, const float* __restrict__ Kl,
                                                    const float* __restrict__ invg, float* __restrict__ k1inv) {
  int b = blockIdx.y;
  int s0 = blockIdx.x * 16;
  __shared__ float KlS[16 * 650];
  __shared__ float invS[16 * 101];
  for (int idx = threadIdx.x; idx < 16 * 640; idx += 256) {
    int h = idx / 640, r = idx % 640;
    KlS[h * 650 + r] = Kl[(size_t)(b * HH + h) * 640 + r];
  }
  for (int idx = threadIdx.x; idx < 1600; idx += 256) {
    int h = idx / 100, r = idx % 100;
    invS[h * 101 + r] = invg[(size_t)(b * HH + h) * 100 + r];
  }
  __syncthreads();
  int sl = threadIdx.x >> 4, h = threadIdx.x & 15;
  int s = s0 + sl;
  size_t qoff = (size_t)(b * SS + s) * QKV_N + h * HDIM;
  float z[10];
#pragma unroll
  for (int m = 0; m < 10; m++) z[m] = 0.f;
  for (int c = 0; c < 8; c++) {
    short8v qv = *(const short8v*)&QKV[qoff + c * 8];
    float qf[8];
#pragma unroll
    for (int jj = 0; jj < 8; jj++) qf[jj] = bf2f(qv[jj]);
#pragma unroll
    for (int m = 0; m < 10; m++) {
      const float* kl = &KlS[h * 650 + m * 64 + c * 8];
      float a = 0.f;
#pragma unroll
      for (int jj = 0; jj < 8; jj++) a += qf[jj] * kl[jj];
      z[m] += a;
    }
  }
  float mx = z[0];
#pragma unroll
  for (int m = 1; m < 10; m++) mx = fmaxf(mx, z[m]);
  float p[10], ssum = 0.f;
#pragma unroll
  for (int m = 0; m < 10; m++) { p[m] = expf(z[m] - mx); ssum += p[m]; }
  float rinv = 1.f / ssum;
  float* dst = &k1inv[((size_t)(b * SS + s) * HH + h) * MLM];
#pragma unroll
  for (int mm = 0; mm < 10; mm++) {
    float a = 0.f;
#pragma unroll
    for (int jjj = 0; jjj < 10; jjj++) a += p[jjj] * invS[h * 101 + jjj * 10 + mm];
    dst[mm] = a * rinv;
  }
}

// ---------------- kv[b,h,m,:] = softmax_s(Ql·K) @ V  (single-pass) ----------------
__global__ __launch_bounds__(256) void k3v_kernel(const short* __restrict__ QKV, const float* __restrict__ Qlg,
                                                  float* __restrict__ kvout) {
  int bh = blockIdx.x;
  int b = bh >> 4, h = bh & 15;
  __shared__ float Kt[64 * 65];
  __shared__ float Vt[64 * 65];
  __shared__ float eS[10 * 64];
  __shared__ float QlS[640];
  __shared__ float denS[10];
  int tid = threadIdx.x;
  int wave = tid >> 6, lane = tid & 63;
  for (int i = tid; i < 640; i += 256) QlS[i] = Qlg[(size_t)bh * 640 + i];
  float myden = 0.f;
  float accn[3] = {0.f, 0.f, 0.f};
  int rowi = tid >> 2;
  int d0 = (tid & 3) * 16;
  for (int s0 = 0; s0 < SS; s0 += 64) {
    __syncthreads();
    if (s0 + rowi < SS) {
      size_t base = (size_t)(b * SS + s0 + rowi) * QKV_N + h * HDIM + d0;
      short8v k0v = *(const short8v*)&QKV[base + 1024];
      short8v k1v = *(const short8v*)&QKV[base + 1024 + 8];
      short8v v0v = *(const short8v*)&QKV[base + 2048];
      short8v v1v = *(const short8v*)&QKV[base + 2048 + 8];
#pragma unroll
      for (int jj = 0; jj < 8; jj++) {
        Kt[rowi * 65 + d0 + jj]     = bf2f(k0v[jj]);
        Kt[rowi * 65 + d0 + 8 + jj] = bf2f(k1v[jj]);
        Vt[rowi * 65 + d0 + jj]     = bf2f(v0v[jj]);
        Vt[rowi * 65 + d0 + 8 + jj] = bf2f(v1v[jj]);
      }
    }
    __syncthreads();
    for (int mb = 0; mb < 12; mb += 4) {
      int m = mb + wave;
      if (m < 10) {
        float z = 0.f;
        const float* kr = &Kt[lane * 65];
        const float* ql = &QlS[m * 64];
        for (int d = 0; d < 64; d++) z += ql[d] * kr[d];
        eS[m * 64 + lane] = (s0 + lane < SS) ? expf(z) : 0.f;
      }
    }
    __syncthreads();
    if (tid < 10) {
      float a = 0.f;
      for (int slj = 0; slj < 64; slj++) a += eS[tid * 64 + slj];
      myden += a;
    }
#pragma unroll
    for (int ii = 0; ii < 3; ii++) {
      int idx = tid + ii * 256;
      if (idx < 640) {
        int m = idx >> 6, d = idx & 63;
        float a = 0.f;
        for (int slj = 0; slj < 64; slj++) a += eS[m * 64 + slj] * Vt[slj * 65 + d];
        accn[ii] += a;
      }
    }
  }
  if (tid < 10) denS[tid] = myden;
  __syncthreads();
#pragma unroll
  for (int ii = 0; ii < 3; ii++) {
    int idx = tid + ii * 256;
    if (idx < 640) {
      int m = idx >> 6;
      kvout[(size_t)bh * 640 + idx] = accn[ii] / denS[m];
    }
  }
}

// ---------------- attn row = k1inv row @ kv, then LayerNorm(g1,be1) -> bf16 ----------------
__global__ __launch_bounds__(256) void attn_ln1(const float* __restrict__ k1inv, const float* __restrict__ kvg,
                                                const float* __restrict__ g1, const float* __restrict__ be1,
                                                short* __restrict__ h1) {
  int blk = blockIdx.x;
  int b = blk / SS;
  __shared__ float pS[160];
  __shared__ float red[8];
  for (int i = threadIdx.x; i < 160; i += 256) pS[i] = k1inv[(size_t)blk * 160 + i];
  __syncthreads();
  float vals[4], s1 = 0.f, s2 = 0.f;
#pragma unroll
  for (int i = 0; i < 4; i++) {
    int e = threadIdx.x + i * 256;
    int h = e >> 6, d = e & 63;
    const float* kvp = &kvg[((size_t)(b * HH + h) * MLM) * HDIM + d];
    const float* pp = &pS[h * 10];
    float a = 0.f;
#pragma unroll
    for (int m = 0; m < 10; m++) a += pp[m] * kvp[m * 64];
    vals[i] = a; s1 += a; s2 += a * a;
  }
#pragma unroll
  for (int off = 32; off; off >>= 1) { s1 += __shfl_down(s1, off); s2 += __shfl_down(s2, off); }
  int wv = threadIdx.x >> 6;
  if ((threadIdx.x & 63) == 0) { red[wv] = s1; red[4 + wv] = s2; }
  __syncthreads();
  float t1 = red[0] + red[1] + red[2] + red[3];
  float t2 = red[4] + red[5] + red[6] + red[7];
  float mean = t1 * (1.f / 1024.f);
  float var = t2 * (1.f / 1024.f) - mean * mean;
  float ninv = rsqrtf(var + 1e-5f);
#pragma unroll
  for (int i = 0; i < 4; i++) {
    int e = threadIdx.x + i * 256;
    h1[(size_t)blk * EE + e] = f2bf((vals[i] - mean) * ninv * g1[e] + be1[e]);
  }
}

// ---------------- LayerNorm(g2,be2) on f32 rows -> bf16 ----------------
__global__ __launch_bounds__(256) void ln2_kernel(const float* __restrict__ h2, const float* __restrict__ g2,
                                                  const float* __restrict__ be2, short* __restrict__ h3) {
  int blk = blockIdx.x;
  __shared__ float red[8];
  float vals[4], s1 = 0.f, s2 = 0.f;
#pragma unroll
  for (int i = 0; i < 4; i++) {
    int e = threadIdx.x + i * 256;
    float a = h2[(size_t)blk * EE + e];
    vals[i] = a; s1 += a; s2 += a * a;
  }
#pragma unroll
  for (int off = 32; off; off >>= 1) { s1 += __shfl_down(s1, off); s2 += __shfl_down(s2, off); }
  int wv = threadIdx.x >> 6;
  if ((threadIdx.x & 63) == 0) { red[wv] = s1; red[4 + wv] = s2; }
  __syncthreads();
  float t1 = red[0] + red[1] + red[2] + red[3];
  float t2 = red[4] + red[5] + red[6] + red[7];
  float mean = t1 * (1.f / 1024.f);
  float var = t2 * (1.f / 1024.f) - mean * mean;
  float ninv = rsqrtf(var + 1e-5f);
#pragma unroll
  for (int i = 0; i < 4; i++) {
    int e = threadIdx.x + i * 256;
    h3[(size_t)blk * EE + e] = f2bf((vals[i] - mean) * ninv * g2[e] + be2[e]);
  }
}

// ---------------- h3 (B,S,E) bf16 -> out (B,E,S) f32 ----------------
__global__ __launch_bounds__(256) void transpose_out(const short* __restrict__ h3, float* __restrict__ outp) {
  __shared__ short tile[64 * 65];
  int b = blockIdx.z;
  int e0 = blockIdx.y * 64;
  int s0 = blockIdx.x * 64;
  int tx = threadIdx.x & 63;
  int ty = threadIdx.x >> 6;
#pragma unroll
  for (int i = 0; i < 16; i++) {
    int r = ty + i * 4;
    int s = s0 + r;
    if (s < SS) tile[r * 65 + tx] = h3[((size_t)b * SS + s) * EE + e0 + tx];
  }
  __syncthreads();
#pragma unroll
  for (int i = 0; i < 16; i++) {
    int c = ty + i * 4;
    int s = s0 + tx;
    if (s < SS) outp[((size_t)b * EE + e0 + c) * SS + s] = bf2f(tile[tx * 65 + c]);
  }
}

// ---------------- workspace layout (~191 MB) ----------------
// slotA: xb -> h1 -> h3 (liveness disjoint); pad rows memset to 0 once.
// slotB: qkv (100.7 MB) + k1ib (at +100.7 MB) -> mid (134.2 MB, full-M)
// h2 (f32, 16000x1024 = exactly out_size) lives in d_out, consumed by ln2
// before transpose_out overwrites d_out.
#define ALIGN_UP(x) (((x) + 255) & ~(size_t)255)
static const size_t SZ_SLOTA = (size_t)MPAD * EE * 2;       // 33.55 MB
static const size_t SZ_QKV   = (size_t)MPAD * QKV_N * 2;    // 100.66 MB
static const size_t SZ_MID   = (size_t)MPAD * MLPD * 2;     // 134.22 MB
static const size_t SZ_WCAT  = (size_t)QKV_N * EE * 2;      // 6.29 MB
static const size_t SZ_W1B   = (size_t)MLPD * EE * 2;       // 8.39 MB
static const size_t SZ_W2B   = (size_t)EE * MLPD * 2;       // 8.39 MB
static const size_t SZ_QL    = (size_t)BB * HH * MLM * HDIM * 4;
static const size_t SZ_K2    = (size_t)BB * HH * 100 * 4;
static const size_t SZ_ST    = 512;

extern "C" void kernel_launch(void* const* d_in, const int* in_sizes, int n_in,
                              void* d_out, int out_size, void* d_ws, size_t ws_size,
                              hipStream_t stream) {
  const float* X   = (const float*)d_in[0];
  const float* Wq  = (const float*)d_in[1];
  const float* bq  = (const float*)d_in[2];
  const float* Wk  = (const float*)d_in[3];
  const float* bk  = (const float*)d_in[4];
  const float* Wv  = (const float*)d_in[5];
  const float* bv  = (const float*)d_in[6];
  const float* g1  = (const float*)d_in[7];
  const float* be1 = (const float*)d_in[8];
  const float* W1  = (const float*)d_in[9];
  const float* b1  = (const float*)d_in[10];
  const float* W2  = (const float*)d_in[11];
  const float* b2  = (const float*)d_in[12];
  const float* g2  = (const float*)d_in[13];
  const float* be2 = (const float*)d_in[14];

  char* ws = (char*)d_ws;
  size_t off = 0;
  char* slotA = ws + off; off += ALIGN_UP(SZ_SLOTA);
  char* slotB = ws + off; off += ALIGN_UP(SZ_MID);
  char* slotD = ws + off; off += ALIGN_UP(SZ_WCAT);
  short* W1b = (short*)(ws + off); off += ALIGN_UP(SZ_W1B);
  short* W2b = (short*)(ws + off); off += ALIGN_UP(SZ_W2B);

  short* xb   = (short*)slotA;
  short* h1   = (short*)slotA;
  short* h3   = (short*)slotA;
  short* qkv  = (short*)slotB;
  short* mid  = (short*)slotB;
  float* k1ib = (float*)(slotB + ALIGN_UP(SZ_QKV));
  short* Wcat = (short*)slotD;
  size_t doff = 0;
  float* Qlm  = (float*)(slotD + doff); doff += ALIGN_UP(SZ_QL);
  float* Klm  = (float*)(slotD + doff); doff += ALIGN_UP(SZ_QL);
  float* k2b  = (float*)(slotD + doff); doff += ALIGN_UP(SZ_K2);
  float* cmaxb= (float*)(slotD + doff); doff += ALIGN_UP(SZ_ST);
  float* rmaxb= (float*)(slotD + doff); doff += ALIGN_UP(SZ_ST);
  float* invb = (float*)(slotD + doff); doff += ALIGN_UP(SZ_K2);
  float* kvb  = (float*)(slotD + doff); doff += ALIGN_UP(SZ_QL);
  float* h2c  = (float*)d_out;   // exactly 16000*1024*4 bytes
  (void)ws_size; (void)in_sizes; (void)n_in; (void)out_size;

  // 0. zero slotA pad rows (so h1 pad rows are 0, not uninitialized bits)
  hipMemsetAsync(slotA + (size_t)BB * SS * EE * 2, 0,
                 (size_t)(MPAD - BB * SS) * EE * 2, stream);
  // 1. transpose/cast X
  transpose_x<<<dim3(63, 32, BB), dim3(32, 8), 0, stream>>>(X, xb);
  // 2. weight casts f32 -> bf16
  cast_f2b<<<2048, 256, 0, stream>>>(Wq, Wcat,             EE * EE);
  cast_f2b<<<2048, 256, 0, stream>>>(Wk, Wcat + EE * EE,   EE * EE);
  cast_f2b<<<2048, 256, 0, stream>>>(Wv, Wcat + 2*EE*EE,   EE * EE);
  cast_f2b<<<4096, 256, 0, stream>>>(W1, W1b, MLPD * EE);
  cast_f2b<<<4096, 256, 0, stream>>>(W2, W2b, EE * MLPD);
  // 3. QKV projection GEMM (Mpad=16384, N=3072, K=1024): 64x12 tiles
  gemm256<<<64 * 12, 512, 0, stream>>>(xb, Wcat, qkv, EE, QKV_N, 0, MPAD, bq, bk, bv);
  // 4. landmarks
  landmarks<<<dim3(BB * HH * MLM, 2), 64, 0, stream>>>(qkv, Qlm, Klm);
  // 5. k2 + stats
  k2stats<<<BB * HH, 128, 0, stream>>>(Qlm, Klm, k2b, cmaxb, rmaxb);
  // 6. iterative inverse
  invk<<<BB * HH, 128, 0, stream>>>(k2b, cmaxb, rmaxb, invb);
  // 7. k1 @ inv
  k1inv_kernel<<<dim3(125, BB), 256, 0, stream>>>(qkv, Klm, invb, k1ib);
  // 8. k3 @ V
  k3v_kernel<<<BB * HH, 256, 0, stream>>>(qkv, Qlm, kvb);
  // 9. attn + LN1
  attn_ln1<<<BB * SS, 256, 0, stream>>>(k1ib, kvb, g1, be1, h1);
  // 10. MLP1 (full M, 64x16 tiles), GELU epilogue -> mid (overwrites qkv+k1ib)
  gemm256<<<64 * 16, 512, 0, stream>>>(h1, W1b, mid, EE, MLPD, 1, MPAD, b1, nullptr, nullptr);
  // 11. MLP2 (full M, 64x4 tiles), f32 out into d_out, store-guarded to 16000 rows
  gemm256<<<64 * 4, 512, 0, stream>>>(mid, W2b, h2c, MLPD, EE, 2, BB * SS, b2, nullptr, nullptr);
  // 12. LN2: d_out(f32) -> h3(bf16, slotA)
  ln2_kernel<<<BB * SS, 256, 0, stream>>>(h2c, g2, be2, h3);
  // 13. transpose to (B,E,S) f32
  transpose_out<<<dim3(32, 16, BB), 256, 0, stream>>>(h3, (float*)d_out);
}